// Round 8
// baseline (275.643 us; speedup 1.0000x reference)
//
#include <hip/hip_runtime.h>

#define L_DIM 1024
#define B_DIM 16
#define D_DIM 1024
#define K_DIM 1024            // = D
#define N_DIM 3072            // = 3*D
#define M_DIM (L_DIM * B_DIM) // 16384
#define CHAINS 16384          // B*D
#define CHUNK 32              // steps per chunk
#define NCHUNK 32             // L / CHUNK

typedef float f32x4 __attribute__((ext_vector_type(4)));
typedef __bf16 bf16x8 __attribute__((ext_vector_type(8)));
typedef unsigned short u16;
typedef unsigned int u32;

__device__ __forceinline__ u16 f2bf(float f) {
  u32 u = __float_as_uint(f);
  u = u + 0x7FFFu + ((u >> 16) & 1u);   // round-to-nearest-even
  return (u16)(u >> 16);
}
__device__ __forceinline__ float bf2f(u16 v) {
  return __uint_as_float(((u32)v) << 16);
}
__device__ __forceinline__ float bf2f_lo(u32 v) {
  return __uint_as_float(v << 16);
}
__device__ __forceinline__ float bf2f_hi(u32 v) {
  return __uint_as_float(v & 0xffff0000u);
}
__device__ __forceinline__ float fexp(float v) {
  return __builtin_amdgcn_exp2f(v * 1.4426950408889634f);
}
__device__ __forceinline__ float sigm(float z) {
  return __builtin_amdgcn_rcpf(1.0f + fexp(-z));
}
__device__ __forceinline__ float ftanh(float v) {
  return 1.0f - 2.0f * __builtin_amdgcn_rcpf(1.0f + fexp(2.0f * v));
}

// ---------------- fused converts: x cast (blocks 0..16383) + W permute (blocks 16384..17151) ----------------
__global__ __launch_bounds__(256) void cvt_fused(const float4* __restrict__ xin,
                                                 ushort4* __restrict__ xout,
                                                 const float* __restrict__ W,
                                                 u16* __restrict__ Wt) {
  if (blockIdx.x < 16384) {
    int i = blockIdx.x * 256 + threadIdx.x;
    float4 v = xin[i];
    ushort4 o;
    o.x = f2bf(v.x); o.y = f2bf(v.y); o.z = f2bf(v.z); o.w = f2bf(v.w);
    xout[i] = o;
  } else {
    __shared__ float tile[64][65];
    int wb = blockIdx.x - 16384;       // 0..767
    int c0 = (wb % 48) * 64;           // N block
    int r0 = (wb / 48) * 64;           // K block
    int tx = threadIdx.x & 63;
    int ty = threadIdx.x >> 6;
#pragma unroll
    for (int i = 0; i < 16; ++i) {
      int row = i * 4 + ty;
      tile[row][tx] = W[(size_t)(r0 + row) * N_DIM + c0 + tx];
    }
    __syncthreads();
#pragma unroll
    for (int i = 0; i < 16; ++i) {
      int crow = i * 4 + ty;
      int c = c0 + crow;
      int nprime = (c % 3) * D_DIM + (c / 3);
      Wt[(size_t)nprime * K_DIM + r0 + tx] = f2bf(tile[tx][crow]);
    }
  }
}

// ---------------- GEMM: 256x256 tile, BK=64, 2-barrier-per-tile free-running halves ----------
// (round-7 version, byte-identical — 101 us, MfmaUtil ~43%, conflicts 0)

#define AS1 __attribute__((address_space(1)))
#define AS3 __attribute__((address_space(3)))
#define STAGE(gp, lp) do { \
  __builtin_amdgcn_global_load_lds((const AS1 void*)(gp), (AS3 void*)(lp), 16, 0, 0); \
  __builtin_amdgcn_global_load_lds((const AS1 void*)((gp) + (size_t)64 * K_DIM), \
                                   (AS3 void*)((lp) + 4096), 16, 0, 0); \
} while (0)

#define QUAD(AI, JB, BF) \
  _Pragma("unroll") \
  for (int i = 0; i < 4; ++i) { \
    _Pragma("unroll") \
    for (int j = 0; j < 2; ++j) { \
      acc[AI + i][JB + j] = __builtin_amdgcn_mfma_f32_16x16x32_bf16(aF[i][0], BF[j][0], acc[AI + i][JB + j], 0, 0, 0); \
      acc[AI + i][JB + j] = __builtin_amdgcn_mfma_f32_16x16x32_bf16(aF[i][1], BF[j][1], acc[AI + i][JB + j], 0, 0, 0); \
    } \
  }

__global__ __launch_bounds__(512, 2) void gemm_kernel(const u16* __restrict__ A,
                                                      const u16* __restrict__ Bt,
                                                      u16* __restrict__ U) {
  __shared__ __align__(16) u16 sm[65536];   // 128 KiB
  const int tid = threadIdx.x;
  const int wave = tid >> 6;
  const int lane = tid & 63;
  const int wm = wave >> 2;        // 0..1  (M)
  const int wn = wave & 3;         // 0..3  (N)
  const int quad = lane >> 4;
  const int l16 = lane & 15;

  // XCD-aware bijective swizzle: 768 blocks, 96 per XCD = 8 contiguous M-rows x 12 N.
  const int flat = blockIdx.y * 12 + blockIdx.x;
  const int swz = (flat & 7) * 96 + (flat >> 3);
  const int m0 = (swz / 12) * 256;
  const int n0 = (swz % 12) * 256;

  // staging source (per-thread): thread t covers HT rows rr and rr+64, 16 B each,
  // global k-slot pre-swizzled so linear LDS dest yields swizzled content.
  const int rr = tid >> 3;                      // 0..63
  const int slot = (tid & 7) ^ (rr & 7);
  const u16* gA = A + (size_t)(m0 + rr) * K_DIM + slot * 8;
  const u16* gB = Bt + (size_t)(n0 + rr) * K_DIM + slot * 8;

  // LDS stage dest bases (u16 units); HW adds lane*16 B.
  u16* ldsA = sm + wave * 512;
  u16* ldsB = sm + 32768 + wave * 512;

  // fragment read bases (swizzled column offsets)
  const int swzu = (l16 & 7) << 3;              // u16 units
  const int c0 = (quad * 8) ^ swzu;             // ks=0
  const int c1 = (32 + quad * 8) ^ swzu;        // ks=1
  const u16* pA = sm + (wm * 128 + l16) * 64;
  const u16* pB = sm + 32768 + (wn * 64 + l16) * 64;

  f32x4 acc[8][4] = {};

  // prologue: A0 -> buf0, B0 -> buf0, B1 -> buf1; vmcnt(4) leaves B1 in flight
  STAGE(gA, ldsA);                                   // A kt0 HT0
  STAGE(gA + (size_t)128 * K_DIM, ldsA + 8192);      // A kt0 HT1
  STAGE(gB, ldsB);                                   // B kt0 HT0
  STAGE(gB + (size_t)128 * K_DIM, ldsB + 8192);      // B kt0 HT1
  STAGE(gB + 64, ldsB + 16384);                      // B kt1 HT0
  STAGE(gB + (size_t)128 * K_DIM + 64, ldsB + 16384 + 8192); // B kt1 HT1
  asm volatile("s_waitcnt vmcnt(4)" ::: "memory");
  __builtin_amdgcn_s_barrier();

  for (int u = 0; u < 16; ++u) {
    const int buf = u & 1;
    const int nb = buf ^ 1;
    const u16* pAb = pA + buf * 16384;
    const u16* pBb = pB + buf * 16384;
    bf16x8 aF[4][2], bLo[2][2], bHi[2][2];

    // ---- half 1: Q(0,0)+Q(0,1)  [reads A mt0-3, all B; stage A[u+1] -> nb] ----
#pragma unroll
    for (int i = 0; i < 4; ++i) {
      aF[i][0] = *(const bf16x8*)(pAb + i * 1024 + c0);
      aF[i][1] = *(const bf16x8*)(pAb + i * 1024 + c1);
    }
#pragma unroll
    for (int j = 0; j < 2; ++j) {
      bLo[j][0] = *(const bf16x8*)(pBb + j * 1024 + c0);
      bLo[j][1] = *(const bf16x8*)(pBb + j * 1024 + c1);
      bHi[j][0] = *(const bf16x8*)(pBb + (2 + j) * 1024 + c0);
      bHi[j][1] = *(const bf16x8*)(pBb + (2 + j) * 1024 + c1);
    }
    if (u < 15) {
      STAGE(gA + (u + 1) * 64, ldsA + nb * 16384);
      STAGE(gA + (size_t)128 * K_DIM + (u + 1) * 64, ldsA + nb * 16384 + 8192);
    }
    __builtin_amdgcn_s_setprio(1);
    QUAD(0, 0, bLo)
    QUAD(0, 2, bHi)
    __builtin_amdgcn_s_setprio(0);
    __builtin_amdgcn_s_barrier();    // last B[u] ds_reads were above -> B-stage safe

    // ---- half 2: Q(1,1)+Q(1,0)  [reads A mt4-7; stage B[u+2] -> buf] ----
#pragma unroll
    for (int i = 0; i < 4; ++i) {
      aF[i][0] = *(const bf16x8*)(pAb + (4 + i) * 1024 + c0);
      aF[i][1] = *(const bf16x8*)(pAb + (4 + i) * 1024 + c1);
    }
    if (u < 14) {
      STAGE(gB + (u + 2) * 64, ldsB + buf * 16384);
      STAGE(gB + (size_t)128 * K_DIM + (u + 2) * 64, ldsB + buf * 16384 + 8192);
    }
    __builtin_amdgcn_s_setprio(1);
    QUAD(4, 2, bHi)
    QUAD(4, 0, bLo)
    __builtin_amdgcn_s_setprio(0);

    // tile-end: A[u+1]+B[u+1] must be in LDS for next tile; B[u+2] stays in flight
    if (u < 14) {
      asm volatile("s_waitcnt vmcnt(4)" ::: "memory");
    } else if (u == 14) {
      asm volatile("s_waitcnt vmcnt(0)" ::: "memory");
    }
    __builtin_amdgcn_s_barrier();
  }

  // epilogue: C/D layout col=lane&15, row=(lane>>4)*4+r
#pragma unroll
  for (int i = 0; i < 8; ++i) {
#pragma unroll
    for (int j = 0; j < 4; ++j) {
      const int col = n0 + wn * 64 + j * 16 + l16;
      const int rb = m0 + wm * 128 + i * 16 + quad * 4;
#pragma unroll
      for (int r = 0; r < 4; ++r)
        U[(size_t)(rb + r) * N_DIM + col] = f2bf(acc[i][j][r]);
    }
  }
}

// ---------------- SRU fused scan: full-line blocks, 2 chains/thread (round-4 exact) --------
// 256 blocks x 1024 threads; block owns 64 consecutive chains (one b, 64 d) = one full
// 128-B line per U-plane row. Threads = (32 pairs) x (32 chunks). Compositions -> LDS;
// 64-lane serial scan; replay. XCD-bijective swizzle over 256 blocks (8 x 32).

__global__ __launch_bounds__(1024) void sru_fused(const u16* __restrict__ U,
                                                  const float* __restrict__ x,
                                                  const float* __restrict__ bias,
                                                  const float* __restrict__ c0,
                                                  float* __restrict__ h,
                                                  float* __restrict__ clast) {
  __shared__ float sA[NCHUNK][64];
  __shared__ float sB[NCHUNK][64];
  __shared__ float sC[NCHUNK][64];

  const int flat = blockIdx.x;                     // 0..255
  const int cb = (flat & 7) * 32 + (flat >> 3);    // chain-block 0..255
  const int b  = cb >> 4;                          // batch 0..15
  const int d0 = (cb & 15) << 6;                   // d base, step 64
  const int t  = threadIdx.x;
  const int pr = t & 31;                           // pair 0..31
  const int j  = t >> 5;                           // chunk 0..31
  const int d2 = d0 + pr * 2;

  const float2 bb1 = *(const float2*)(bias + d2);

  // ---- phase A: per-(chunk, chain-pair) affine composition ----
  {
    const u16* p = U + (size_t)(j * CHUNK * B_DIM + b) * N_DIM + d2;
    float A0 = 1.0f, A1 = 1.0f, B0 = 0.0f, B1 = 0.0f;
#pragma unroll 4
    for (int s = 0; s < CHUNK; ++s) {
      u32 w0 = *(const u32*)p;
      u32 w1 = *(const u32*)(p + D_DIM);
      float u0a = bf2f_lo(w0), u0b = bf2f_hi(w0);
      float g1a = sigm(bf2f_lo(w1) + bb1.x);
      float g1b = sigm(bf2f_hi(w1) + bb1.y);
      B0 = (B0 - u0a) * g1a + u0a;
      B1 = (B1 - u0b) * g1b + u0b;
      A0 *= g1a;
      A1 *= g1b;
      p += (size_t)B_DIM * N_DIM;
    }
    *(float2*)&sA[j][pr * 2] = make_float2(A0, A1);
    *(float2*)&sB[j][pr * 2] = make_float2(B0, B1);
  }
  __syncthreads();

  // ---- phase B: serial scan over 32 chunks, one lane per chain ----
  if (t < 64) {
    const int chain = cb * 64 + t;   // = b*D + d0 + t
    float c = c0[chain];
#pragma unroll
    for (int jj = 0; jj < NCHUNK; ++jj) {
      sC[jj][t] = c;
      c = sA[jj][t] * c + sB[jj][t];
    }
    clast[chain] = c;
  }
  __syncthreads();

  // ---- phase C: replay with h output ----
  {
    const float2 bb2 = *(const float2*)(bias + D_DIM + d2);
    float2 c = *(const float2*)&sC[j][pr * 2];
    const size_t m0 = (size_t)(j * CHUNK * B_DIM + b);
    const u16* p = U + m0 * N_DIM + d2;
    const float* xp = x + m0 * D_DIM + d2;
    float* hp = h + m0 * D_DIM + d2;
#pragma unroll 4
    for (int s = 0; s < CHUNK; ++s) {
      u32 w0 = *(const u32*)p;
      u32 w1 = *(const u32*)(p + D_DIM);
      u32 w2 = *(const u32*)(p + 2 * D_DIM);
      float2 xv = *(const float2*)xp;
      float u0a = bf2f_lo(w0), u0b = bf2f_hi(w0);
      float g1a = sigm(bf2f_lo(w1) + bb1.x);
      float g1b = sigm(bf2f_hi(w1) + bb1.y);
      float g2a = sigm(bf2f_lo(w2) + bb2.x);
      float g2b = sigm(bf2f_hi(w2) + bb2.y);
      c.x = (c.x - u0a) * g1a + u0a;
      c.y = (c.y - u0b) * g1b + u0b;
      float2 hv;
      hv.x = (ftanh(c.x) - xv.x) * g2a + xv.x;
      hv.y = (ftanh(c.y) - xv.y) * g2b + xv.y;
      *(float2*)hp = hv;
      p += (size_t)B_DIM * N_DIM;
      xp += B_DIM * D_DIM;
      hp += B_DIM * D_DIM;
    }
  }
}

extern "C" void kernel_launch(void* const* d_in, const int* in_sizes, int n_in,
                              void* d_out, int out_size, void* d_ws, size_t ws_size,
                              hipStream_t stream) {
  const float* x = (const float*)d_in[0];     // L*B*D
  const float* W = (const float*)d_in[1];     // K x 3D
  const float* bias = (const float*)d_in[2];  // 2D
  const float* c0 = (const float*)d_in[3];    // B*D
  float* out = (float*)d_out;

  char* ws = (char*)d_ws;
  u16* xb = (u16*)ws;                               // 32 MiB
  u16* wt = (u16*)(ws + 33554432);                  // 6 MiB
  u16* U = (u16*)(ws + 33554432 + 6291456);         // 96 MiB

  cvt_fused<<<16384 + 768, 256, 0, stream>>>((const float4*)x, (ushort4*)xb, W, wt);
  gemm_kernel<<<dim3(N_DIM / 256, M_DIM / 256), 512, 0, stream>>>(xb, wt, U);
  sru_fused<<<256, 1024, 0, stream>>>(U, x, bias, c0, out, out + (size_t)M_DIM * D_DIM);
}

// Round 9
// 264.087 us; speedup vs baseline: 1.0438x; 1.0438x over previous
//
#include <hip/hip_runtime.h>

#define L_DIM 1024
#define B_DIM 16
#define D_DIM 1024
#define K_DIM 1024            // = D
#define N_DIM 3072            // = 3*D
#define M_DIM (L_DIM * B_DIM) // 16384
#define CHAINS 16384          // B*D

typedef float f32x4 __attribute__((ext_vector_type(4)));
typedef __bf16 bf16x8 __attribute__((ext_vector_type(8)));
typedef unsigned short u16;
typedef unsigned int u32;

__device__ __forceinline__ u16 f2bf(float f) {
  u32 u = __float_as_uint(f);
  u = u + 0x7FFFu + ((u >> 16) & 1u);   // round-to-nearest-even
  return (u16)(u >> 16);
}
__device__ __forceinline__ float bf2f(u16 v) {
  return __uint_as_float(((u32)v) << 16);
}
__device__ __forceinline__ float bf2f_lo(u32 v) {
  return __uint_as_float(v << 16);
}
__device__ __forceinline__ float bf2f_hi(u32 v) {
  return __uint_as_float(v & 0xffff0000u);
}
__device__ __forceinline__ float fexp(float v) {
  return __builtin_amdgcn_exp2f(v * 1.4426950408889634f);
}
__device__ __forceinline__ float sigm(float z) {
  return __builtin_amdgcn_rcpf(1.0f + fexp(-z));
}
__device__ __forceinline__ float ftanh(float v) {
  return 1.0f - 2.0f * __builtin_amdgcn_rcpf(1.0f + fexp(2.0f * v));
}

// ---------------- fused converts: x cast (blocks 0..16383) + W permute (blocks 16384..17151) ----------------
__global__ __launch_bounds__(256) void cvt_fused(const float4* __restrict__ xin,
                                                 ushort4* __restrict__ xout,
                                                 const float* __restrict__ W,
                                                 u16* __restrict__ Wt) {
  if (blockIdx.x < 16384) {
    int i = blockIdx.x * 256 + threadIdx.x;
    float4 v = xin[i];
    ushort4 o;
    o.x = f2bf(v.x); o.y = f2bf(v.y); o.z = f2bf(v.z); o.w = f2bf(v.w);
    xout[i] = o;
  } else {
    __shared__ float tile[64][65];
    int wb = blockIdx.x - 16384;       // 0..767
    int c0 = (wb % 48) * 64;           // N block
    int r0 = (wb / 48) * 64;           // K block
    int tx = threadIdx.x & 63;
    int ty = threadIdx.x >> 6;
#pragma unroll
    for (int i = 0; i < 16; ++i) {
      int row = i * 4 + ty;
      tile[row][tx] = W[(size_t)(r0 + row) * N_DIM + c0 + tx];
    }
    __syncthreads();
#pragma unroll
    for (int i = 0; i < 16; ++i) {
      int crow = i * 4 + ty;
      int c = c0 + crow;
      int nprime = (c % 3) * D_DIM + (c / 3);
      Wt[(size_t)nprime * K_DIM + r0 + tx] = f2bf(tile[tx][crow]);
    }
  }
}

// ---------------- GEMM: 256x256 tile, BK=64, 2-barrier-per-tile free-running halves ----------
// (round-7 version, byte-identical — 101 us, MfmaUtil ~43%, conflicts 0)

#define AS1 __attribute__((address_space(1)))
#define AS3 __attribute__((address_space(3)))
#define STAGE(gp, lp) do { \
  __builtin_amdgcn_global_load_lds((const AS1 void*)(gp), (AS3 void*)(lp), 16, 0, 0); \
  __builtin_amdgcn_global_load_lds((const AS1 void*)((gp) + (size_t)64 * K_DIM), \
                                   (AS3 void*)((lp) + 4096), 16, 0, 0); \
} while (0)

#define QUAD(AI, JB, BF) \
  _Pragma("unroll") \
  for (int i = 0; i < 4; ++i) { \
    _Pragma("unroll") \
    for (int j = 0; j < 2; ++j) { \
      acc[AI + i][JB + j] = __builtin_amdgcn_mfma_f32_16x16x32_bf16(aF[i][0], BF[j][0], acc[AI + i][JB + j], 0, 0, 0); \
      acc[AI + i][JB + j] = __builtin_amdgcn_mfma_f32_16x16x32_bf16(aF[i][1], BF[j][1], acc[AI + i][JB + j], 0, 0, 0); \
    } \
  }

__global__ __launch_bounds__(512, 2) void gemm_kernel(const u16* __restrict__ A,
                                                      const u16* __restrict__ Bt,
                                                      u16* __restrict__ U) {
  __shared__ __align__(16) u16 sm[65536];   // 128 KiB
  const int tid = threadIdx.x;
  const int wave = tid >> 6;
  const int lane = tid & 63;
  const int wm = wave >> 2;        // 0..1  (M)
  const int wn = wave & 3;         // 0..3  (N)
  const int quad = lane >> 4;
  const int l16 = lane & 15;

  // XCD-aware bijective swizzle: 768 blocks, 96 per XCD = 8 contiguous M-rows x 12 N.
  const int flat = blockIdx.y * 12 + blockIdx.x;
  const int swz = (flat & 7) * 96 + (flat >> 3);
  const int m0 = (swz / 12) * 256;
  const int n0 = (swz % 12) * 256;

  // staging source (per-thread): thread t covers HT rows rr and rr+64, 16 B each,
  // global k-slot pre-swizzled so linear LDS dest yields swizzled content.
  const int rr = tid >> 3;                      // 0..63
  const int slot = (tid & 7) ^ (rr & 7);
  const u16* gA = A + (size_t)(m0 + rr) * K_DIM + slot * 8;
  const u16* gB = Bt + (size_t)(n0 + rr) * K_DIM + slot * 8;

  // LDS stage dest bases (u16 units); HW adds lane*16 B.
  u16* ldsA = sm + wave * 512;
  u16* ldsB = sm + 32768 + wave * 512;

  // fragment read bases (swizzled column offsets)
  const int swzu = (l16 & 7) << 3;              // u16 units
  const int c0 = (quad * 8) ^ swzu;             // ks=0
  const int c1 = (32 + quad * 8) ^ swzu;        // ks=1
  const u16* pA = sm + (wm * 128 + l16) * 64;
  const u16* pB = sm + 32768 + (wn * 64 + l16) * 64;

  f32x4 acc[8][4] = {};

  // prologue: A0 -> buf0, B0 -> buf0, B1 -> buf1; vmcnt(4) leaves B1 in flight
  STAGE(gA, ldsA);                                   // A kt0 HT0
  STAGE(gA + (size_t)128 * K_DIM, ldsA + 8192);      // A kt0 HT1
  STAGE(gB, ldsB);                                   // B kt0 HT0
  STAGE(gB + (size_t)128 * K_DIM, ldsB + 8192);      // B kt0 HT1
  STAGE(gB + 64, ldsB + 16384);                      // B kt1 HT0
  STAGE(gB + (size_t)128 * K_DIM + 64, ldsB + 16384 + 8192); // B kt1 HT1
  asm volatile("s_waitcnt vmcnt(4)" ::: "memory");
  __builtin_amdgcn_s_barrier();

  for (int u = 0; u < 16; ++u) {
    const int buf = u & 1;
    const int nb = buf ^ 1;
    const u16* pAb = pA + buf * 16384;
    const u16* pBb = pB + buf * 16384;
    bf16x8 aF[4][2], bLo[2][2], bHi[2][2];

    // ---- half 1: Q(0,0)+Q(0,1)  [reads A mt0-3, all B; stage A[u+1] -> nb] ----
#pragma unroll
    for (int i = 0; i < 4; ++i) {
      aF[i][0] = *(const bf16x8*)(pAb + i * 1024 + c0);
      aF[i][1] = *(const bf16x8*)(pAb + i * 1024 + c1);
    }
#pragma unroll
    for (int j = 0; j < 2; ++j) {
      bLo[j][0] = *(const bf16x8*)(pBb + j * 1024 + c0);
      bLo[j][1] = *(const bf16x8*)(pBb + j * 1024 + c1);
      bHi[j][0] = *(const bf16x8*)(pBb + (2 + j) * 1024 + c0);
      bHi[j][1] = *(const bf16x8*)(pBb + (2 + j) * 1024 + c1);
    }
    if (u < 15) {
      STAGE(gA + (u + 1) * 64, ldsA + nb * 16384);
      STAGE(gA + (size_t)128 * K_DIM + (u + 1) * 64, ldsA + nb * 16384 + 8192);
    }
    __builtin_amdgcn_s_setprio(1);
    QUAD(0, 0, bLo)
    QUAD(0, 2, bHi)
    __builtin_amdgcn_s_setprio(0);
    __builtin_amdgcn_s_barrier();    // last B[u] ds_reads were above -> B-stage safe

    // ---- half 2: Q(1,1)+Q(1,0)  [reads A mt4-7; stage B[u+2] -> buf] ----
#pragma unroll
    for (int i = 0; i < 4; ++i) {
      aF[i][0] = *(const bf16x8*)(pAb + (4 + i) * 1024 + c0);
      aF[i][1] = *(const bf16x8*)(pAb + (4 + i) * 1024 + c1);
    }
    if (u < 14) {
      STAGE(gB + (u + 2) * 64, ldsB + buf * 16384);
      STAGE(gB + (size_t)128 * K_DIM + (u + 2) * 64, ldsB + buf * 16384 + 8192);
    }
    __builtin_amdgcn_s_setprio(1);
    QUAD(4, 2, bHi)
    QUAD(4, 0, bLo)
    __builtin_amdgcn_s_setprio(0);

    // tile-end: A[u+1]+B[u+1] must be in LDS for next tile; B[u+2] stays in flight
    if (u < 14) {
      asm volatile("s_waitcnt vmcnt(4)" ::: "memory");
    } else if (u == 14) {
      asm volatile("s_waitcnt vmcnt(0)" ::: "memory");
    }
    __builtin_amdgcn_s_barrier();
  }

  // epilogue: C/D layout col=lane&15, row=(lane>>4)*4+r
#pragma unroll
  for (int i = 0; i < 8; ++i) {
#pragma unroll
    for (int j = 0; j < 4; ++j) {
      const int col = n0 + wn * 64 + j * 16 + l16;
      const int rb = m0 + wm * 128 + i * 16 + quad * 4;
#pragma unroll
      for (int r = 0; r < 4; ++r)
        U[(size_t)(rb + r) * N_DIM + col] = f2bf(acc[i][j][r]);
    }
  }
}

// ---------------- SRU one-pass pipelined scan ----------------
// 256 blocks x 1024 threads; block owns 64 chains (one b, 64 d). Chunks of 32 steps
// processed IN TIME ORDER (true c carried in wave-0 registers) -> U read exactly once.
// Per iter k: [A: load+unpack chunk k -> LDS(cur) | H: emit h for chunk k-1 from LDS(prv)]
// barrier [S: wave 0 walks chunk k's 32 steps from registers, posts c_t -> LDS(cur)] barrier.
// LDS fp32 [2][64][33] x4 (u0,g1,g2,c) = 67.6 KB; pad 33 keeps all accesses <=2-way.

__global__ __launch_bounds__(1024) void sru_onepass(const u16* __restrict__ U,
                                                    const float* __restrict__ x,
                                                    const float* __restrict__ bias,
                                                    const float* __restrict__ c0,
                                                    float* __restrict__ h,
                                                    float* __restrict__ clast) {
  __shared__ float sU0[2][64][33];
  __shared__ float sG1[2][64][33];
  __shared__ float sG2[2][64][33];
  __shared__ float sCC[2][64][33];

  const int flat = blockIdx.x;                   // 0..255, XCD-bijective (8 x 32)
  const int cb = (flat & 7) * 32 + (flat >> 3);  // chain-block
  const int b  = cb >> 4;                        // batch
  const int d0 = (cb & 15) << 6;                 // d base
  const int t  = threadIdx.x;
  const int s  = t >> 5;                         // step-in-chunk 0..31
  const int ch = (t & 31) * 2;                   // chain base (pair)

  const float2 bb1 = *(const float2*)(bias + d0 + ch);
  const float2 bb2 = *(const float2*)(bias + D_DIM + d0 + ch);

  float creg = 0.0f;
  if (t < 64) creg = c0[cb * 64 + t];

  for (int k = 0; k <= 32; ++k) {
    const int cur = k & 1;
    const int prv = cur ^ 1;

    if (k < 32) {   // A: load + unpack chunk k
      const size_t m = (size_t)((k * 32 + s) * 16 + b);
      const u16* p = U + m * N_DIM + d0 + ch;
      u32 w0 = *(const u32*)p;
      u32 w1 = *(const u32*)(p + D_DIM);
      u32 w2 = *(const u32*)(p + 2 * D_DIM);
      sU0[cur][ch][s]     = bf2f_lo(w0);
      sU0[cur][ch + 1][s] = bf2f_hi(w0);
      sG1[cur][ch][s]     = sigm(bf2f_lo(w1) + bb1.x);
      sG1[cur][ch + 1][s] = sigm(bf2f_hi(w1) + bb1.y);
      sG2[cur][ch][s]     = sigm(bf2f_lo(w2) + bb2.x);
      sG2[cur][ch + 1][s] = sigm(bf2f_hi(w2) + bb2.y);
    }
    if (k >= 1) {   // H: emit h for chunk k-1
      const size_t m = (size_t)(((k - 1) * 32 + s) * 16 + b);
      float ca = sCC[prv][ch][s];
      float cbv = sCC[prv][ch + 1][s];
      float ga = sG2[prv][ch][s];
      float gb = sG2[prv][ch + 1][s];
      float2 xv = *(const float2*)(x + m * D_DIM + d0 + ch);
      float2 hv;
      hv.x = (ftanh(ca) - xv.x) * ga + xv.x;
      hv.y = (ftanh(cbv) - xv.y) * gb + xv.y;
      *(float2*)(h + m * D_DIM + d0 + ch) = hv;
    }
    __syncthreads();

    if (k < 32 && t < 64) {   // S: wave 0, lane t owns chain t; registers only in the walk
      float lu[16], lg[16];
#pragma unroll
      for (int q = 0; q < 16; ++q) { lu[q] = sU0[cur][t][q]; lg[q] = sG1[cur][t][q]; }
#pragma unroll
      for (int q = 0; q < 16; ++q) {
        creg = (creg - lu[q]) * lg[q] + lu[q];
        sCC[cur][t][q] = creg;
      }
#pragma unroll
      for (int q = 0; q < 16; ++q) { lu[q] = sU0[cur][t][16 + q]; lg[q] = sG1[cur][t][16 + q]; }
#pragma unroll
      for (int q = 0; q < 16; ++q) {
        creg = (creg - lu[q]) * lg[q] + lu[q];
        sCC[cur][t][16 + q] = creg;
      }
    }
    __syncthreads();
  }

  if (t < 64) clast[cb * 64 + t] = creg;
}

extern "C" void kernel_launch(void* const* d_in, const int* in_sizes, int n_in,
                              void* d_out, int out_size, void* d_ws, size_t ws_size,
                              hipStream_t stream) {
  const float* x = (const float*)d_in[0];     // L*B*D
  const float* W = (const float*)d_in[1];     // K x 3D
  const float* bias = (const float*)d_in[2];  // 2D
  const float* c0 = (const float*)d_in[3];    // B*D
  float* out = (float*)d_out;

  char* ws = (char*)d_ws;
  u16* xb = (u16*)ws;                               // 32 MiB
  u16* wt = (u16*)(ws + 33554432);                  // 6 MiB
  u16* U = (u16*)(ws + 33554432 + 6291456);         // 96 MiB

  cvt_fused<<<16384 + 768, 256, 0, stream>>>((const float4*)x, (ushort4*)xb, W, wt);
  gemm_kernel<<<dim3(N_DIM / 256, M_DIM / 256), 512, 0, stream>>>(xb, wt, U);
  sru_onepass<<<256, 1024, 0, stream>>>(U, x, bias, c0, out, out + (size_t)M_DIM * D_DIM);
}

// Round 10
// 261.272 us; speedup vs baseline: 1.0550x; 1.0108x over previous
//
#include <hip/hip_runtime.h>

#define L_DIM 1024
#define B_DIM 16
#define D_DIM 1024
#define K_DIM 1024            // = D
#define N_DIM 3072            // = 3*D
#define M_DIM (L_DIM * B_DIM) // 16384
#define CHAINS 16384          // B*D

typedef float f32x4 __attribute__((ext_vector_type(4)));
typedef __bf16 bf16x8 __attribute__((ext_vector_type(8)));
typedef unsigned short u16;
typedef unsigned int u32;

__device__ __forceinline__ u16 f2bf(float f) {
  u32 u = __float_as_uint(f);
  u = u + 0x7FFFu + ((u >> 16) & 1u);   // round-to-nearest-even
  return (u16)(u >> 16);
}
__device__ __forceinline__ float bf2f(u16 v) {
  return __uint_as_float(((u32)v) << 16);
}
__device__ __forceinline__ float bf2f_lo(u32 v) {
  return __uint_as_float(v << 16);
}
__device__ __forceinline__ float bf2f_hi(u32 v) {
  return __uint_as_float(v & 0xffff0000u);
}
__device__ __forceinline__ float fexp(float v) {
  return __builtin_amdgcn_exp2f(v * 1.4426950408889634f);
}
__device__ __forceinline__ float sigm(float z) {
  return __builtin_amdgcn_rcpf(1.0f + fexp(-z));
}
__device__ __forceinline__ float ftanh(float v) {
  return 1.0f - 2.0f * __builtin_amdgcn_rcpf(1.0f + fexp(2.0f * v));
}

// ---------------- fused converts: x cast (blocks 0..16383) + W permute (blocks 16384..17151) ----------------
__global__ __launch_bounds__(256) void cvt_fused(const float4* __restrict__ xin,
                                                 ushort4* __restrict__ xout,
                                                 const float* __restrict__ W,
                                                 u16* __restrict__ Wt) {
  if (blockIdx.x < 16384) {
    int i = blockIdx.x * 256 + threadIdx.x;
    float4 v = xin[i];
    ushort4 o;
    o.x = f2bf(v.x); o.y = f2bf(v.y); o.z = f2bf(v.z); o.w = f2bf(v.w);
    xout[i] = o;
  } else {
    __shared__ float tile[64][65];
    int wb = blockIdx.x - 16384;       // 0..767
    int c0 = (wb % 48) * 64;           // N block
    int r0 = (wb / 48) * 64;           // K block
    int tx = threadIdx.x & 63;
    int ty = threadIdx.x >> 6;
#pragma unroll
    for (int i = 0; i < 16; ++i) {
      int row = i * 4 + ty;
      tile[row][tx] = W[(size_t)(r0 + row) * N_DIM + c0 + tx];
    }
    __syncthreads();
#pragma unroll
    for (int i = 0; i < 16; ++i) {
      int crow = i * 4 + ty;
      int c = c0 + crow;
      int nprime = (c % 3) * D_DIM + (c / 3);
      Wt[(size_t)nprime * K_DIM + r0 + tx] = f2bf(tile[tx][crow]);
    }
  }
}

// ---------------- GEMM: 256x256 tile, BK=64, 2-barrier-per-tile free-running halves ----------
// (round-7 version, byte-identical — 101 us, MfmaUtil ~43%, conflicts 0)

#define AS1 __attribute__((address_space(1)))
#define AS3 __attribute__((address_space(3)))
#define STAGE(gp, lp) do { \
  __builtin_amdgcn_global_load_lds((const AS1 void*)(gp), (AS3 void*)(lp), 16, 0, 0); \
  __builtin_amdgcn_global_load_lds((const AS1 void*)((gp) + (size_t)64 * K_DIM), \
                                   (AS3 void*)((lp) + 4096), 16, 0, 0); \
} while (0)

#define QUAD(AI, JB, BF) \
  _Pragma("unroll") \
  for (int i = 0; i < 4; ++i) { \
    _Pragma("unroll") \
    for (int j = 0; j < 2; ++j) { \
      acc[AI + i][JB + j] = __builtin_amdgcn_mfma_f32_16x16x32_bf16(aF[i][0], BF[j][0], acc[AI + i][JB + j], 0, 0, 0); \
      acc[AI + i][JB + j] = __builtin_amdgcn_mfma_f32_16x16x32_bf16(aF[i][1], BF[j][1], acc[AI + i][JB + j], 0, 0, 0); \
    } \
  }

__global__ __launch_bounds__(512, 2) void gemm_kernel(const u16* __restrict__ A,
                                                      const u16* __restrict__ Bt,
                                                      u16* __restrict__ U) {
  __shared__ __align__(16) u16 sm[65536];   // 128 KiB
  const int tid = threadIdx.x;
  const int wave = tid >> 6;
  const int lane = tid & 63;
  const int wm = wave >> 2;        // 0..1  (M)
  const int wn = wave & 3;         // 0..3  (N)
  const int quad = lane >> 4;
  const int l16 = lane & 15;

  // XCD-aware bijective swizzle: 768 blocks, 96 per XCD = 8 contiguous M-rows x 12 N.
  const int flat = blockIdx.y * 12 + blockIdx.x;
  const int swz = (flat & 7) * 96 + (flat >> 3);
  const int m0 = (swz / 12) * 256;
  const int n0 = (swz % 12) * 256;

  // staging source (per-thread): thread t covers HT rows rr and rr+64, 16 B each,
  // global k-slot pre-swizzled so linear LDS dest yields swizzled content.
  const int rr = tid >> 3;                      // 0..63
  const int slot = (tid & 7) ^ (rr & 7);
  const u16* gA = A + (size_t)(m0 + rr) * K_DIM + slot * 8;
  const u16* gB = Bt + (size_t)(n0 + rr) * K_DIM + slot * 8;

  // LDS stage dest bases (u16 units); HW adds lane*16 B.
  u16* ldsA = sm + wave * 512;
  u16* ldsB = sm + 32768 + wave * 512;

  // fragment read bases (swizzled column offsets)
  const int swzu = (l16 & 7) << 3;              // u16 units
  const int c0 = (quad * 8) ^ swzu;             // ks=0
  const int c1 = (32 + quad * 8) ^ swzu;        // ks=1
  const u16* pA = sm + (wm * 128 + l16) * 64;
  const u16* pB = sm + 32768 + (wn * 64 + l16) * 64;

  f32x4 acc[8][4] = {};

  // prologue: A0 -> buf0, B0 -> buf0, B1 -> buf1; vmcnt(4) leaves B1 in flight
  STAGE(gA, ldsA);                                   // A kt0 HT0
  STAGE(gA + (size_t)128 * K_DIM, ldsA + 8192);      // A kt0 HT1
  STAGE(gB, ldsB);                                   // B kt0 HT0
  STAGE(gB + (size_t)128 * K_DIM, ldsB + 8192);      // B kt0 HT1
  STAGE(gB + 64, ldsB + 16384);                      // B kt1 HT0
  STAGE(gB + (size_t)128 * K_DIM + 64, ldsB + 16384 + 8192); // B kt1 HT1
  asm volatile("s_waitcnt vmcnt(4)" ::: "memory");
  __builtin_amdgcn_s_barrier();

  for (int u = 0; u < 16; ++u) {
    const int buf = u & 1;
    const int nb = buf ^ 1;
    const u16* pAb = pA + buf * 16384;
    const u16* pBb = pB + buf * 16384;
    bf16x8 aF[4][2], bLo[2][2], bHi[2][2];

    // ---- half 1: Q(0,0)+Q(0,1)  [reads A mt0-3, all B; stage A[u+1] -> nb] ----
#pragma unroll
    for (int i = 0; i < 4; ++i) {
      aF[i][0] = *(const bf16x8*)(pAb + i * 1024 + c0);
      aF[i][1] = *(const bf16x8*)(pAb + i * 1024 + c1);
    }
#pragma unroll
    for (int j = 0; j < 2; ++j) {
      bLo[j][0] = *(const bf16x8*)(pBb + j * 1024 + c0);
      bLo[j][1] = *(const bf16x8*)(pBb + j * 1024 + c1);
      bHi[j][0] = *(const bf16x8*)(pBb + (2 + j) * 1024 + c0);
      bHi[j][1] = *(const bf16x8*)(pBb + (2 + j) * 1024 + c1);
    }
    if (u < 15) {
      STAGE(gA + (u + 1) * 64, ldsA + nb * 16384);
      STAGE(gA + (size_t)128 * K_DIM + (u + 1) * 64, ldsA + nb * 16384 + 8192);
    }
    __builtin_amdgcn_s_setprio(1);
    QUAD(0, 0, bLo)
    QUAD(0, 2, bHi)
    __builtin_amdgcn_s_setprio(0);
    __builtin_amdgcn_s_barrier();    // last B[u] ds_reads were above -> B-stage safe

    // ---- half 2: Q(1,1)+Q(1,0)  [reads A mt4-7; stage B[u+2] -> buf] ----
#pragma unroll
    for (int i = 0; i < 4; ++i) {
      aF[i][0] = *(const bf16x8*)(pAb + (4 + i) * 1024 + c0);
      aF[i][1] = *(const bf16x8*)(pAb + (4 + i) * 1024 + c1);
    }
    if (u < 14) {
      STAGE(gB + (u + 2) * 64, ldsB + buf * 16384);
      STAGE(gB + (size_t)128 * K_DIM + (u + 2) * 64, ldsB + buf * 16384 + 8192);
    }
    __builtin_amdgcn_s_setprio(1);
    QUAD(4, 2, bHi)
    QUAD(4, 0, bLo)
    __builtin_amdgcn_s_setprio(0);

    // tile-end: A[u+1]+B[u+1] must be in LDS for next tile; B[u+2] stays in flight
    if (u < 14) {
      asm volatile("s_waitcnt vmcnt(4)" ::: "memory");
    } else if (u == 14) {
      asm volatile("s_waitcnt vmcnt(0)" ::: "memory");
    }
    __builtin_amdgcn_s_barrier();
  }

  // epilogue: C/D layout col=lane&15, row=(lane>>4)*4+r
#pragma unroll
  for (int i = 0; i < 8; ++i) {
#pragma unroll
    for (int j = 0; j < 4; ++j) {
      const int col = n0 + wn * 64 + j * 16 + l16;
      const int rb = m0 + wm * 128 + i * 16 + quad * 4;
#pragma unroll
      for (int r = 0; r < 4; ++r)
        U[(size_t)(rb + r) * N_DIM + col] = f2bf(acc[i][j][r]);
    }
  }
}

// ---------------- SRU one-pass pipelined scan, T14 prefetch, 2 blocks/CU ----------------
// 512 blocks x 512 threads; block owns 32 chains (one b, 32 d). Chunks of 32 steps in time
// order; true c carried in lane registers -> U read once. Per iter k:
//   A: write PREFETCHED chunk-k regs -> LDS[cur]; issue chunk-k+1 U loads + chunk-k x load
//   H: emit h for chunk k-1 from LDS[prv] + prefetched x regs
//   lgkmcnt(0); s_barrier  (raw barrier: prefetch loads stay in flight)
//   S: lanes 0-31 of wave 0 walk chunk k from LDS->regs, post c_t -> LDS[cur]
//   lgkmcnt(0); s_barrier
// LDS fp32 [2][32][33] x4 = 33.8 KB -> 2 blocks/CU at grid 512 (cross-block TLP).

__global__ __launch_bounds__(512) void sru_onepass(const u16* __restrict__ U,
                                                   const float* __restrict__ x,
                                                   const float* __restrict__ bias,
                                                   const float* __restrict__ c0,
                                                   float* __restrict__ h,
                                                   float* __restrict__ clast) {
  __shared__ float sU0[2][32][33];
  __shared__ float sG1[2][32][33];
  __shared__ float sG2[2][32][33];
  __shared__ float sCC[2][32][33];

  const int flat = blockIdx.x;                   // 0..511; XCD-bijective, adjacent-d same XCD
  const int cb = (flat & 7) * 64 + (flat >> 3);  // chain-block 0..511
  const int b  = cb >> 5;                        // batch 0..15
  const int d0 = (cb & 31) << 5;                 // d base, step 32
  const int t  = threadIdx.x;
  const int s  = t >> 4;                         // step-in-chunk 0..31
  const int ch = (t & 15) * 2;                   // chain pair base 0..30
  const int d2 = d0 + ch;

  const float2 bb1 = *(const float2*)(bias + d2);
  const float2 bb2 = *(const float2*)(bias + D_DIM + d2);

  float creg = 0.0f;
  if (t < 32) creg = c0[cb * 32 + t];

  // prefetch chunk 0 (U planes) and x[chunk 0]
  u32 w0, w1, w2;
  float2 xv;
  {
    const size_t m = (size_t)(s * 16 + b);
    const u16* p = U + m * N_DIM + d2;
    w0 = *(const u32*)p;
    w1 = *(const u32*)(p + D_DIM);
    w2 = *(const u32*)(p + 2 * D_DIM);
    xv = *(const float2*)(x + m * D_DIM + d2);
  }

  for (int k = 0; k <= 32; ++k) {
    const int cur = k & 1;
    const int prv = cur ^ 1;

    float2 xcons = xv;   // x[chunk k-1] (consumed by H below when k>=1)

    if (k < 32) {
      // A: unpack prefetched chunk k -> LDS[cur]  (compiler inserts vmcnt wait on w0..w2)
      sU0[cur][ch][s]     = bf2f_lo(w0);
      sU0[cur][ch + 1][s] = bf2f_hi(w0);
      sG1[cur][ch][s]     = sigm(bf2f_lo(w1) + bb1.x);
      sG1[cur][ch + 1][s] = sigm(bf2f_hi(w1) + bb1.y);
      sG2[cur][ch][s]     = sigm(bf2f_lo(w2) + bb2.x);
      sG2[cur][ch + 1][s] = sigm(bf2f_hi(w2) + bb2.y);
      if (k < 31) {   // issue U prefetch for chunk k+1
        const size_t m = (size_t)(((k + 1) * 32 + s) * 16 + b);
        const u16* p = U + m * N_DIM + d2;
        w0 = *(const u32*)p;
        w1 = *(const u32*)(p + D_DIM);
        w2 = *(const u32*)(p + 2 * D_DIM);
      }
      // issue x prefetch for chunk k (consumed at iter k+1)
      xv = *(const float2*)(x + (size_t)((k * 32 + s) * 16 + b) * D_DIM + d2);
    }
    if (k >= 1) {
      // H: emit h for chunk k-1 from LDS[prv]
      const size_t m = (size_t)(((k - 1) * 32 + s) * 16 + b);
      float ca  = sCC[prv][ch][s];
      float cbv = sCC[prv][ch + 1][s];
      float ga  = sG2[prv][ch][s];
      float gb  = sG2[prv][ch + 1][s];
      float2 hv;
      hv.x = (ftanh(ca) - xcons.x) * ga + xcons.x;
      hv.y = (ftanh(cbv) - xcons.y) * gb + xcons.y;
      *(float2*)(h + m * D_DIM + d2) = hv;
    }
    asm volatile("s_waitcnt lgkmcnt(0)" ::: "memory");
    __builtin_amdgcn_s_barrier();

    if (k < 32 && t < 32) {   // S: lane t owns chain t; walk 32 steps from registers
      float lu[16], lg[16];
#pragma unroll
      for (int q = 0; q < 16; ++q) { lu[q] = sU0[cur][t][q]; lg[q] = sG1[cur][t][q]; }
#pragma unroll
      for (int q = 0; q < 16; ++q) {
        creg = (creg - lu[q]) * lg[q] + lu[q];
        sCC[cur][t][q] = creg;
      }
#pragma unroll
      for (int q = 0; q < 16; ++q) { lu[q] = sU0[cur][t][16 + q]; lg[q] = sG1[cur][t][16 + q]; }
#pragma unroll
      for (int q = 0; q < 16; ++q) {
        creg = (creg - lu[q]) * lg[q] + lu[q];
        sCC[cur][t][16 + q] = creg;
      }
    }
    asm volatile("s_waitcnt lgkmcnt(0)" ::: "memory");
    __builtin_amdgcn_s_barrier();
  }

  if (t < 32) clast[cb * 32 + t] = creg;
}

extern "C" void kernel_launch(void* const* d_in, const int* in_sizes, int n_in,
                              void* d_out, int out_size, void* d_ws, size_t ws_size,
                              hipStream_t stream) {
  const float* x = (const float*)d_in[0];     // L*B*D
  const float* W = (const float*)d_in[1];     // K x 3D
  const float* bias = (const float*)d_in[2];  // 2D
  const float* c0 = (const float*)d_in[3];    // B*D
  float* out = (float*)d_out;

  char* ws = (char*)d_ws;
  u16* xb = (u16*)ws;                               // 32 MiB
  u16* wt = (u16*)(ws + 33554432);                  // 6 MiB
  u16* U = (u16*)(ws + 33554432 + 6291456);         // 96 MiB

  cvt_fused<<<16384 + 768, 256, 0, stream>>>((const float4*)x, (ushort4*)xb, W, wt);
  gemm_kernel<<<dim3(N_DIM / 256, M_DIM / 256), 512, 0, stream>>>(xb, wt, U);
  sru_onepass<<<512, 512, 0, stream>>>(U, x, bias, c0, out, out + (size_t)M_DIM * D_DIM);
}

// Round 11
// 260.662 us; speedup vs baseline: 1.0575x; 1.0023x over previous
//
#include <hip/hip_runtime.h>

#define L_DIM 1024
#define B_DIM 16
#define D_DIM 1024
#define K_DIM 1024            // = D
#define N_DIM 3072            // = 3*D
#define M_DIM (L_DIM * B_DIM) // 16384
#define CHAINS 16384          // B*D

typedef float f32x4 __attribute__((ext_vector_type(4)));
typedef __bf16 bf16x8 __attribute__((ext_vector_type(8)));
typedef unsigned short u16;
typedef unsigned int u32;

__device__ __forceinline__ u16 f2bf(float f) {
  u32 u = __float_as_uint(f);
  u = u + 0x7FFFu + ((u >> 16) & 1u);   // round-to-nearest-even
  return (u16)(u >> 16);
}
__device__ __forceinline__ float bf2f(u16 v) {
  return __uint_as_float(((u32)v) << 16);
}
__device__ __forceinline__ float bf2f_lo(u32 v) {
  return __uint_as_float(v << 16);
}
__device__ __forceinline__ float bf2f_hi(u32 v) {
  return __uint_as_float(v & 0xffff0000u);
}
__device__ __forceinline__ float fexp(float v) {
  return __builtin_amdgcn_exp2f(v * 1.4426950408889634f);
}
__device__ __forceinline__ float sigm(float z) {
  return __builtin_amdgcn_rcpf(1.0f + fexp(-z));
}
__device__ __forceinline__ float ftanh(float v) {
  return 1.0f - 2.0f * __builtin_amdgcn_rcpf(1.0f + fexp(2.0f * v));
}

// ---------------- fused converts: x cast (blocks 0..16383) + W permute (blocks 16384..17151) ----------------
__global__ __launch_bounds__(256) void cvt_fused(const float4* __restrict__ xin,
                                                 ushort4* __restrict__ xout,
                                                 const float* __restrict__ W,
                                                 u16* __restrict__ Wt) {
  if (blockIdx.x < 16384) {
    int i = blockIdx.x * 256 + threadIdx.x;
    float4 v = xin[i];
    ushort4 o;
    o.x = f2bf(v.x); o.y = f2bf(v.y); o.z = f2bf(v.z); o.w = f2bf(v.w);
    xout[i] = o;
  } else {
    __shared__ float tile[64][65];
    int wb = blockIdx.x - 16384;       // 0..767
    int c0 = (wb % 48) * 64;           // N block
    int r0 = (wb / 48) * 64;           // K block
    int tx = threadIdx.x & 63;
    int ty = threadIdx.x >> 6;
#pragma unroll
    for (int i = 0; i < 16; ++i) {
      int row = i * 4 + ty;
      tile[row][tx] = W[(size_t)(r0 + row) * N_DIM + c0 + tx];
    }
    __syncthreads();
#pragma unroll
    for (int i = 0; i < 16; ++i) {
      int crow = i * 4 + ty;
      int c = c0 + crow;
      int nprime = (c % 3) * D_DIM + (c / 3);
      Wt[(size_t)nprime * K_DIM + r0 + tx] = f2bf(tile[tx][crow]);
    }
  }
}

// ---------------- GEMM: 256x256 tile, BK=64, ONE barrier per tile (B triple-buffered) --------
// vs round-7 (2 barriers/tile): the mid-tile barrier existed only to make B-staging WAR-safe
// against B[u] reads in the same double-buffer slot. B now rotates over 3 slots (slot u%3):
// stage B[u+2] -> slot (u+2)%3 = (u-1)%3, whose last reads completed before the END barrier
// of tile u-1 -> WAR-safe with a single tile-end barrier. A stays double-buffered (+1
// lookahead; A[u+1] -> slot (u+1)&1, last read at tile u-1, same one-barrier argument).
// vmcnt ledger (identical to R7): entering tile u, B[u+1](4) in flight; issue A[u+1](4) +
// B[u+2](4) -> 12; tile-end vmcnt(4) retires A[u+1]+B[u+1], leaves B[u+2]. u==14 -> vmcnt(0).
// LDS: A 2x32 KB + B 3x32 KB = 160 KiB (full CU LDS; gfx950 allows 160 KB/workgroup).

#define AS1 __attribute__((address_space(1)))
#define AS3 __attribute__((address_space(3)))
#define STAGE(gp, lp) do { \
  __builtin_amdgcn_global_load_lds((const AS1 void*)(gp), (AS3 void*)(lp), 16, 0, 0); \
  __builtin_amdgcn_global_load_lds((const AS1 void*)((gp) + (size_t)64 * K_DIM), \
                                   (AS3 void*)((lp) + 4096), 16, 0, 0); \
} while (0)

#define QUAD(AI, JB, BF) \
  _Pragma("unroll") \
  for (int i = 0; i < 4; ++i) { \
    _Pragma("unroll") \
    for (int j = 0; j < 2; ++j) { \
      acc[AI + i][JB + j] = __builtin_amdgcn_mfma_f32_16x16x32_bf16(aF[i][0], BF[j][0], acc[AI + i][JB + j], 0, 0, 0); \
      acc[AI + i][JB + j] = __builtin_amdgcn_mfma_f32_16x16x32_bf16(aF[i][1], BF[j][1], acc[AI + i][JB + j], 0, 0, 0); \
    } \
  }

__global__ __launch_bounds__(512, 2) void gemm_kernel(const u16* __restrict__ A,
                                                      const u16* __restrict__ Bt,
                                                      u16* __restrict__ U) {
  __shared__ __align__(16) u16 sm[81920];   // 160 KiB: A[2][16384] @0, B[3][16384] @32768
  const int tid = threadIdx.x;
  const int wave = tid >> 6;
  const int lane = tid & 63;
  const int wm = wave >> 2;        // 0..1  (M)
  const int wn = wave & 3;         // 0..3  (N)
  const int quad = lane >> 4;
  const int l16 = lane & 15;

  // XCD-aware bijective swizzle: 768 blocks, 96 per XCD = 8 contiguous M-rows x 12 N.
  const int flat = blockIdx.y * 12 + blockIdx.x;
  const int swz = (flat & 7) * 96 + (flat >> 3);
  const int m0 = (swz / 12) * 256;
  const int n0 = (swz % 12) * 256;

  // staging source (per-thread): thread t covers HT rows rr and rr+64, 16 B each,
  // global k-slot pre-swizzled so linear LDS dest yields swizzled content.
  const int rr = tid >> 3;                      // 0..63
  const int slot = (tid & 7) ^ (rr & 7);
  const u16* gA = A + (size_t)(m0 + rr) * K_DIM + slot * 8;
  const u16* gB = Bt + (size_t)(n0 + rr) * K_DIM + slot * 8;

  // LDS stage dest bases (u16 units); HW adds lane*16 B.
  u16* ldsA = sm + wave * 512;
  u16* ldsB = sm + 32768 + wave * 512;

  // fragment read bases (swizzled column offsets)
  const int swzu = (l16 & 7) << 3;              // u16 units
  const int c0 = (quad * 8) ^ swzu;             // ks=0
  const int c1 = (32 + quad * 8) ^ swzu;        // ks=1
  const u16* pA = sm + (wm * 128 + l16) * 64;
  const u16* pB = sm + 32768 + (wn * 64 + l16) * 64;

  f32x4 acc[8][4] = {};

  // prologue: A0 -> Aslot0, B0 -> Bslot0, B1 -> Bslot1; vmcnt(4) leaves B1 in flight
  STAGE(gA, ldsA);                                   // A kt0 HT0
  STAGE(gA + (size_t)128 * K_DIM, ldsA + 8192);      // A kt0 HT1
  STAGE(gB, ldsB);                                   // B kt0 HT0
  STAGE(gB + (size_t)128 * K_DIM, ldsB + 8192);      // B kt0 HT1
  STAGE(gB + 64, ldsB + 16384);                      // B kt1 HT0
  STAGE(gB + (size_t)128 * K_DIM + 64, ldsB + 16384 + 8192); // B kt1 HT1
  asm volatile("s_waitcnt vmcnt(4)" ::: "memory");
  __builtin_amdgcn_s_barrier();

  int su = 0;   // B read slot  = u%3
  int st = 2;   // B stage slot = (u+2)%3
  for (int u = 0; u < 16; ++u) {
    const int abuf = u & 1;
    const int anb = abuf ^ 1;
    const u16* pAb = pA + abuf * 16384;
    const u16* pBb = pB + su * 16384;
    bf16x8 aF[4][2], bLo[2][2], bHi[2][2];

    // ---- ds_read A mt0-3 + all B; stage A[u+1] -> A slot anb ----
#pragma unroll
    for (int i = 0; i < 4; ++i) {
      aF[i][0] = *(const bf16x8*)(pAb + i * 1024 + c0);
      aF[i][1] = *(const bf16x8*)(pAb + i * 1024 + c1);
    }
#pragma unroll
    for (int j = 0; j < 2; ++j) {
      bLo[j][0] = *(const bf16x8*)(pBb + j * 1024 + c0);
      bLo[j][1] = *(const bf16x8*)(pBb + j * 1024 + c1);
      bHi[j][0] = *(const bf16x8*)(pBb + (2 + j) * 1024 + c0);
      bHi[j][1] = *(const bf16x8*)(pBb + (2 + j) * 1024 + c1);
    }
    if (u < 15) {
      STAGE(gA + (u + 1) * 64, ldsA + anb * 16384);
      STAGE(gA + (size_t)128 * K_DIM + (u + 1) * 64, ldsA + anb * 16384 + 8192);
    }
    __builtin_amdgcn_s_setprio(1);
    QUAD(0, 0, bLo)
    QUAD(0, 2, bHi)
    __builtin_amdgcn_s_setprio(0);

    // ---- ds_read A mt4-7; stage B[u+2] -> B slot st ----
#pragma unroll
    for (int i = 0; i < 4; ++i) {
      aF[i][0] = *(const bf16x8*)(pAb + (4 + i) * 1024 + c0);
      aF[i][1] = *(const bf16x8*)(pAb + (4 + i) * 1024 + c1);
    }
    if (u < 14) {
      STAGE(gB + (u + 2) * 64, ldsB + st * 16384);
      STAGE(gB + (size_t)128 * K_DIM + (u + 2) * 64, ldsB + st * 16384 + 8192);
    }
    __builtin_amdgcn_s_setprio(1);
    QUAD(4, 2, bHi)
    QUAD(4, 0, bLo)
    __builtin_amdgcn_s_setprio(0);

    // tile-end: A[u+1]+B[u+1] must be in LDS for next tile; B[u+2] stays in flight
    if (u < 14) {
      asm volatile("s_waitcnt vmcnt(4)" ::: "memory");
    } else if (u == 14) {
      asm volatile("s_waitcnt vmcnt(0)" ::: "memory");
    }
    __builtin_amdgcn_s_barrier();

    su = (su == 2) ? 0 : su + 1;
    st = (st == 2) ? 0 : st + 1;
  }

  // epilogue: C/D layout col=lane&15, row=(lane>>4)*4+r
#pragma unroll
  for (int i = 0; i < 8; ++i) {
#pragma unroll
    for (int j = 0; j < 4; ++j) {
      const int col = n0 + wn * 64 + j * 16 + l16;
      const int rb = m0 + wm * 128 + i * 16 + quad * 4;
#pragma unroll
      for (int r = 0; r < 4; ++r)
        U[(size_t)(rb + r) * N_DIM + col] = f2bf(acc[i][j][r]);
    }
  }
}

// ---------------- SRU one-pass pipelined scan, T14 prefetch, 2 blocks/CU (round-10 exact) ----
__global__ __launch_bounds__(512) void sru_onepass(const u16* __restrict__ U,
                                                   const float* __restrict__ x,
                                                   const float* __restrict__ bias,
                                                   const float* __restrict__ c0,
                                                   float* __restrict__ h,
                                                   float* __restrict__ clast) {
  __shared__ float sU0[2][32][33];
  __shared__ float sG1[2][32][33];
  __shared__ float sG2[2][32][33];
  __shared__ float sCC[2][32][33];

  const int flat = blockIdx.x;                   // 0..511; XCD-bijective, adjacent-d same XCD
  const int cb = (flat & 7) * 64 + (flat >> 3);  // chain-block 0..511
  const int b  = cb >> 5;                        // batch 0..15
  const int d0 = (cb & 31) << 5;                 // d base, step 32
  const int t  = threadIdx.x;
  const int s  = t >> 4;                         // step-in-chunk 0..31
  const int ch = (t & 15) * 2;                   // chain pair base 0..30
  const int d2 = d0 + ch;

  const float2 bb1 = *(const float2*)(bias + d2);
  const float2 bb2 = *(const float2*)(bias + D_DIM + d2);

  float creg = 0.0f;
  if (t < 32) creg = c0[cb * 32 + t];

  // prefetch chunk 0 (U planes) and x[chunk 0]
  u32 w0, w1, w2;
  float2 xv;
  {
    const size_t m = (size_t)(s * 16 + b);
    const u16* p = U + m * N_DIM + d2;
    w0 = *(const u32*)p;
    w1 = *(const u32*)(p + D_DIM);
    w2 = *(const u32*)(p + 2 * D_DIM);
    xv = *(const float2*)(x + m * D_DIM + d2);
  }

  for (int k = 0; k <= 32; ++k) {
    const int cur = k & 1;
    const int prv = cur ^ 1;

    float2 xcons = xv;   // x[chunk k-1] (consumed by H below when k>=1)

    if (k < 32) {
      // A: unpack prefetched chunk k -> LDS[cur]  (compiler inserts vmcnt wait on w0..w2)
      sU0[cur][ch][s]     = bf2f_lo(w0);
      sU0[cur][ch + 1][s] = bf2f_hi(w0);
      sG1[cur][ch][s]     = sigm(bf2f_lo(w1) + bb1.x);
      sG1[cur][ch + 1][s] = sigm(bf2f_hi(w1) + bb1.y);
      sG2[cur][ch][s]     = sigm(bf2f_lo(w2) + bb2.x);
      sG2[cur][ch + 1][s] = sigm(bf2f_hi(w2) + bb2.y);
      if (k < 31) {   // issue U prefetch for chunk k+1
        const size_t m = (size_t)(((k + 1) * 32 + s) * 16 + b);
        const u16* p = U + m * N_DIM + d2;
        w0 = *(const u32*)p;
        w1 = *(const u32*)(p + D_DIM);
        w2 = *(const u32*)(p + 2 * D_DIM);
      }
      // issue x prefetch for chunk k (consumed at iter k+1)
      xv = *(const float2*)(x + (size_t)((k * 32 + s) * 16 + b) * D_DIM + d2);
    }
    if (k >= 1) {
      // H: emit h for chunk k-1 from LDS[prv]
      const size_t m = (size_t)(((k - 1) * 32 + s) * 16 + b);
      float ca  = sCC[prv][ch][s];
      float cbv = sCC[prv][ch + 1][s];
      float ga  = sG2[prv][ch][s];
      float gb  = sG2[prv][ch + 1][s];
      float2 hv;
      hv.x = (ftanh(ca) - xcons.x) * ga + xcons.x;
      hv.y = (ftanh(cbv) - xcons.y) * gb + xcons.y;
      *(float2*)(h + m * D_DIM + d2) = hv;
    }
    asm volatile("s_waitcnt lgkmcnt(0)" ::: "memory");
    __builtin_amdgcn_s_barrier();

    if (k < 32 && t < 32) {   // S: lane t owns chain t; walk 32 steps from registers
      float lu[16], lg[16];
#pragma unroll
      for (int q = 0; q < 16; ++q) { lu[q] = sU0[cur][t][q]; lg[q] = sG1[cur][t][q]; }
#pragma unroll
      for (int q = 0; q < 16; ++q) {
        creg = (creg - lu[q]) * lg[q] + lu[q];
        sCC[cur][t][q] = creg;
      }
#pragma unroll
      for (int q = 0; q < 16; ++q) { lu[q] = sU0[cur][t][16 + q]; lg[q] = sG1[cur][t][16 + q]; }
#pragma unroll
      for (int q = 0; q < 16; ++q) {
        creg = (creg - lu[q]) * lg[q] + lu[q];
        sCC[cur][t][16 + q] = creg;
      }
    }
    asm volatile("s_waitcnt lgkmcnt(0)" ::: "memory");
    __builtin_amdgcn_s_barrier();
  }

  if (t < 32) clast[cb * 32 + t] = creg;
}

extern "C" void kernel_launch(void* const* d_in, const int* in_sizes, int n_in,
                              void* d_out, int out_size, void* d_ws, size_t ws_size,
                              hipStream_t stream) {
  const float* x = (const float*)d_in[0];     // L*B*D
  const float* W = (const float*)d_in[1];     // K x 3D
  const float* bias = (const float*)d_in[2];  // 2D
  const float* c0 = (const float*)d_in[3];    // B*D
  float* out = (float*)d_out;

  char* ws = (char*)d_ws;
  u16* xb = (u16*)ws;                               // 32 MiB
  u16* wt = (u16*)(ws + 33554432);                  // 6 MiB
  u16* U = (u16*)(ws + 33554432 + 6291456);         // 96 MiB

  cvt_fused<<<16384 + 768, 256, 0, stream>>>((const float4*)x, (ushort4*)xb, W, wt);
  gemm_kernel<<<dim3(N_DIM / 256, M_DIM / 256), 512, 0, stream>>>(xb, wt, U);
  sru_onepass<<<512, 512, 0, stream>>>(U, x, bias, c0, out, out + (size_t)M_DIM * D_DIM);
}

// Round 12
// 255.241 us; speedup vs baseline: 1.0799x; 1.0212x over previous
//
#include <hip/hip_runtime.h>

#define L_DIM 1024
#define B_DIM 16
#define D_DIM 1024
#define K_DIM 1024            // = D
#define N_DIM 3072            // = 3*D
#define M_DIM (L_DIM * B_DIM) // 16384
#define CHAINS 16384          // B*D

typedef float f32x4 __attribute__((ext_vector_type(4)));
typedef __bf16 bf16x8 __attribute__((ext_vector_type(8)));
typedef unsigned short u16;
typedef unsigned int u32;

__device__ __forceinline__ u16 f2bf(float f) {
  u32 u = __float_as_uint(f);
  u = u + 0x7FFFu + ((u >> 16) & 1u);   // round-to-nearest-even
  return (u16)(u >> 16);
}
__device__ __forceinline__ float bf2f(u16 v) {
  return __uint_as_float(((u32)v) << 16);
}
__device__ __forceinline__ float bf2f_lo(u32 v) {
  return __uint_as_float(v << 16);
}
__device__ __forceinline__ float bf2f_hi(u32 v) {
  return __uint_as_float(v & 0xffff0000u);
}
__device__ __forceinline__ float fexp(float v) {
  return __builtin_amdgcn_exp2f(v * 1.4426950408889634f);
}
__device__ __forceinline__ float sigm(float z) {
  return __builtin_amdgcn_rcpf(1.0f + fexp(-z));
}
__device__ __forceinline__ float ftanh(float v) {
  return 1.0f - 2.0f * __builtin_amdgcn_rcpf(1.0f + fexp(2.0f * v));
}

// ---------------- fused converts: x cast (blocks 0..16383) + W permute (blocks 16384..17151) ----------------
__global__ __launch_bounds__(256) void cvt_fused(const float4* __restrict__ xin,
                                                 ushort4* __restrict__ xout,
                                                 const float* __restrict__ W,
                                                 u16* __restrict__ Wt) {
  if (blockIdx.x < 16384) {
    int i = blockIdx.x * 256 + threadIdx.x;
    float4 v = xin[i];
    ushort4 o;
    o.x = f2bf(v.x); o.y = f2bf(v.y); o.z = f2bf(v.z); o.w = f2bf(v.w);
    xout[i] = o;
  } else {
    __shared__ float tile[64][65];
    int wb = blockIdx.x - 16384;       // 0..767
    int c0 = (wb % 48) * 64;           // N block
    int r0 = (wb / 48) * 64;           // K block
    int tx = threadIdx.x & 63;
    int ty = threadIdx.x >> 6;
#pragma unroll
    for (int i = 0; i < 16; ++i) {
      int row = i * 4 + ty;
      tile[row][tx] = W[(size_t)(r0 + row) * N_DIM + c0 + tx];
    }
    __syncthreads();
#pragma unroll
    for (int i = 0; i < 16; ++i) {
      int crow = i * 4 + ty;
      int c = c0 + crow;
      int nprime = (c % 3) * D_DIM + (c / 3);
      Wt[(size_t)nprime * K_DIM + r0 + tx] = f2bf(tile[tx][crow]);
    }
  }
}

// ---------------- GEMM: 256x256 tile, BK=64, ONE barrier per tile, B triple-buffered --------
// (round-11 version, byte-identical — ~99 us, MfmaUtil ~44%, conflicts 0, LDS 160 KiB)

#define AS1 __attribute__((address_space(1)))
#define AS3 __attribute__((address_space(3)))
#define STAGE(gp, lp) do { \
  __builtin_amdgcn_global_load_lds((const AS1 void*)(gp), (AS3 void*)(lp), 16, 0, 0); \
  __builtin_amdgcn_global_load_lds((const AS1 void*)((gp) + (size_t)64 * K_DIM), \
                                   (AS3 void*)((lp) + 4096), 16, 0, 0); \
} while (0)

#define QUAD(AI, JB, BF) \
  _Pragma("unroll") \
  for (int i = 0; i < 4; ++i) { \
    _Pragma("unroll") \
    for (int j = 0; j < 2; ++j) { \
      acc[AI + i][JB + j] = __builtin_amdgcn_mfma_f32_16x16x32_bf16(aF[i][0], BF[j][0], acc[AI + i][JB + j], 0, 0, 0); \
      acc[AI + i][JB + j] = __builtin_amdgcn_mfma_f32_16x16x32_bf16(aF[i][1], BF[j][1], acc[AI + i][JB + j], 0, 0, 0); \
    } \
  }

__global__ __launch_bounds__(512, 2) void gemm_kernel(const u16* __restrict__ A,
                                                      const u16* __restrict__ Bt,
                                                      u16* __restrict__ U) {
  __shared__ __align__(16) u16 sm[81920];   // 160 KiB: A[2][16384] @0, B[3][16384] @32768
  const int tid = threadIdx.x;
  const int wave = tid >> 6;
  const int lane = tid & 63;
  const int wm = wave >> 2;        // 0..1  (M)
  const int wn = wave & 3;         // 0..3  (N)
  const int quad = lane >> 4;
  const int l16 = lane & 15;

  // XCD-aware bijective swizzle: 768 blocks, 96 per XCD = 8 contiguous M-rows x 12 N.
  const int flat = blockIdx.y * 12 + blockIdx.x;
  const int swz = (flat & 7) * 96 + (flat >> 3);
  const int m0 = (swz / 12) * 256;
  const int n0 = (swz % 12) * 256;

  // staging source (per-thread): thread t covers HT rows rr and rr+64, 16 B each,
  // global k-slot pre-swizzled so linear LDS dest yields swizzled content.
  const int rr = tid >> 3;                      // 0..63
  const int slot = (tid & 7) ^ (rr & 7);
  const u16* gA = A + (size_t)(m0 + rr) * K_DIM + slot * 8;
  const u16* gB = Bt + (size_t)(n0 + rr) * K_DIM + slot * 8;

  // LDS stage dest bases (u16 units); HW adds lane*16 B.
  u16* ldsA = sm + wave * 512;
  u16* ldsB = sm + 32768 + wave * 512;

  // fragment read bases (swizzled column offsets)
  const int swzu = (l16 & 7) << 3;              // u16 units
  const int c0 = (quad * 8) ^ swzu;             // ks=0
  const int c1 = (32 + quad * 8) ^ swzu;        // ks=1
  const u16* pA = sm + (wm * 128 + l16) * 64;
  const u16* pB = sm + 32768 + (wn * 64 + l16) * 64;

  f32x4 acc[8][4] = {};

  // prologue: A0 -> Aslot0, B0 -> Bslot0, B1 -> Bslot1; vmcnt(4) leaves B1 in flight
  STAGE(gA, ldsA);                                   // A kt0 HT0
  STAGE(gA + (size_t)128 * K_DIM, ldsA + 8192);      // A kt0 HT1
  STAGE(gB, ldsB);                                   // B kt0 HT0
  STAGE(gB + (size_t)128 * K_DIM, ldsB + 8192);      // B kt0 HT1
  STAGE(gB + 64, ldsB + 16384);                      // B kt1 HT0
  STAGE(gB + (size_t)128 * K_DIM + 64, ldsB + 16384 + 8192); // B kt1 HT1
  asm volatile("s_waitcnt vmcnt(4)" ::: "memory");
  __builtin_amdgcn_s_barrier();

  int su = 0;   // B read slot  = u%3
  int st = 2;   // B stage slot = (u+2)%3
  for (int u = 0; u < 16; ++u) {
    const int abuf = u & 1;
    const int anb = abuf ^ 1;
    const u16* pAb = pA + abuf * 16384;
    const u16* pBb = pB + su * 16384;
    bf16x8 aF[4][2], bLo[2][2], bHi[2][2];

    // ---- ds_read A mt0-3 + all B; stage A[u+1] -> A slot anb ----
#pragma unroll
    for (int i = 0; i < 4; ++i) {
      aF[i][0] = *(const bf16x8*)(pAb + i * 1024 + c0);
      aF[i][1] = *(const bf16x8*)(pAb + i * 1024 + c1);
    }
#pragma unroll
    for (int j = 0; j < 2; ++j) {
      bLo[j][0] = *(const bf16x8*)(pBb + j * 1024 + c0);
      bLo[j][1] = *(const bf16x8*)(pBb + j * 1024 + c1);
      bHi[j][0] = *(const bf16x8*)(pBb + (2 + j) * 1024 + c0);
      bHi[j][1] = *(const bf16x8*)(pBb + (2 + j) * 1024 + c1);
    }
    if (u < 15) {
      STAGE(gA + (u + 1) * 64, ldsA + anb * 16384);
      STAGE(gA + (size_t)128 * K_DIM + (u + 1) * 64, ldsA + anb * 16384 + 8192);
    }
    __builtin_amdgcn_s_setprio(1);
    QUAD(0, 0, bLo)
    QUAD(0, 2, bHi)
    __builtin_amdgcn_s_setprio(0);

    // ---- ds_read A mt4-7; stage B[u+2] -> B slot st ----
#pragma unroll
    for (int i = 0; i < 4; ++i) {
      aF[i][0] = *(const bf16x8*)(pAb + (4 + i) * 1024 + c0);
      aF[i][1] = *(const bf16x8*)(pAb + (4 + i) * 1024 + c1);
    }
    if (u < 14) {
      STAGE(gB + (u + 2) * 64, ldsB + st * 16384);
      STAGE(gB + (size_t)128 * K_DIM + (u + 2) * 64, ldsB + st * 16384 + 8192);
    }
    __builtin_amdgcn_s_setprio(1);
    QUAD(4, 2, bHi)
    QUAD(4, 0, bLo)
    __builtin_amdgcn_s_setprio(0);

    // tile-end: A[u+1]+B[u+1] must be in LDS for next tile; B[u+2] stays in flight
    if (u < 14) {
      asm volatile("s_waitcnt vmcnt(4)" ::: "memory");
    } else if (u == 14) {
      asm volatile("s_waitcnt vmcnt(0)" ::: "memory");
    }
    __builtin_amdgcn_s_barrier();

    su = (su == 2) ? 0 : su + 1;
    st = (st == 2) ? 0 : st + 1;
  }

  // epilogue: C/D layout col=lane&15, row=(lane>>4)*4+r
#pragma unroll
  for (int i = 0; i < 8; ++i) {
#pragma unroll
    for (int j = 0; j < 4; ++j) {
      const int col = n0 + wn * 64 + j * 16 + l16;
      const int rb = m0 + wm * 128 + i * 16 + quad * 4;
#pragma unroll
      for (int r = 0; r < 4; ++r)
        U[(size_t)(rb + r) * N_DIM + col] = f2bf(acc[i][j][r]);
    }
  }
}

// ---------------- SRU one-pass scan, S || H wave specialization ----------------
// 512 blocks x 512 threads; block owns 32 chains. vs round-10: the serial chunk-walk S(k)
// (wave 0, lanes 0-31) and the h-emit H(k-1) (previously a separate barrier-bounded phase
// with 7 waves idle during S) now run CONCURRENTLY between the same barrier pair:
//   iter k: A(k): unpack prefetched U chunk k -> LDS[cur]; issue U[k+1] + x[k] prefetches
//           lgkmcnt(0); s_barrier                                  (bar1)
//           S(k) on threads 0-31 (sCC[cur] <- walk)  ||  H(k-1) on threads 64-511
//             (reads sCC[prv], sG2[prv], prefetched x regs; writes h)
//           lgkmcnt(0); s_barrier                                  (bar2)
// Hazards: S/H touch disjoint parity buffers; A(k+1) overwrites LDS[prv] only after bar2;
// sCC[cur] written by S(k) is read by H(k) after bar2(k)+bar1(k+1). H item remap: threads
// 64-511 cover items 0-447, threads 64-127 also items 448-511 (wave 0 does no H).
// LDS 33.8 KB -> 2 blocks/CU.

__global__ __launch_bounds__(512) void sru_onepass(const u16* __restrict__ U,
                                                   const float* __restrict__ x,
                                                   const float* __restrict__ bias,
                                                   const float* __restrict__ c0,
                                                   float* __restrict__ h,
                                                   float* __restrict__ clast) {
  __shared__ float sU0[2][32][33];
  __shared__ float sG1[2][32][33];
  __shared__ float sG2[2][32][33];
  __shared__ float sCC[2][32][33];

  const int flat = blockIdx.x;                   // 0..511; XCD-bijective, adjacent-d same XCD
  const int cb = (flat & 7) * 64 + (flat >> 3);  // chain-block 0..511
  const int b  = cb >> 5;                        // batch 0..15
  const int d0 = (cb & 31) << 5;                 // d base, step 32
  const int t  = threadIdx.x;
  const int s  = t >> 4;                         // A-map: step-in-chunk 0..31
  const int ch = (t & 15) * 2;                   // A-map: chain pair base 0..30
  const int d2 = d0 + ch;

  const float2 bb1 = *(const float2*)(bias + d2);
  const float2 bb2 = *(const float2*)(bias + D_DIM + d2);

  // H-map: thread t>=64 handles item1 = t-64; threads 64..127 also item2 = 448+(t-64)
  const int i1 = t - 64;
  const int s1 = i1 >> 4, ch1 = (i1 & 15) * 2;
  const int i2 = 448 + (t - 64);
  const int s2 = i2 >> 4, ch2 = (i2 & 15) * 2;

  float creg = 0.0f;
  if (t < 32) creg = c0[cb * 32 + t];

  // prefetch chunk 0: U planes (A-map) and x (H-map)
  u32 w0, w1, w2;
  float2 xv1, xv2;
  {
    const size_t m = (size_t)(s * 16 + b);
    const u16* p = U + m * N_DIM + d2;
    w0 = *(const u32*)p;
    w1 = *(const u32*)(p + D_DIM);
    w2 = *(const u32*)(p + 2 * D_DIM);
  }
  if (t >= 64)             xv1 = *(const float2*)(x + (size_t)(s1 * 16 + b) * D_DIM + d0 + ch1);
  if (t >= 64 && t < 128)  xv2 = *(const float2*)(x + (size_t)(s2 * 16 + b) * D_DIM + d0 + ch2);

  for (int k = 0; k <= 32; ++k) {
    const int cur = k & 1;
    const int prv = cur ^ 1;

    float2 xc1 = xv1, xc2 = xv2;   // x[chunk k-1] for H below

    if (k < 32) {
      // A: unpack prefetched chunk k -> LDS[cur]
      sU0[cur][ch][s]     = bf2f_lo(w0);
      sU0[cur][ch + 1][s] = bf2f_hi(w0);
      sG1[cur][ch][s]     = sigm(bf2f_lo(w1) + bb1.x);
      sG1[cur][ch + 1][s] = sigm(bf2f_hi(w1) + bb1.y);
      sG2[cur][ch][s]     = sigm(bf2f_lo(w2) + bb2.x);
      sG2[cur][ch + 1][s] = sigm(bf2f_hi(w2) + bb2.y);
      if (k < 31) {   // issue U prefetch for chunk k+1
        const size_t m = (size_t)(((k + 1) * 32 + s) * 16 + b);
        const u16* p = U + m * N_DIM + d2;
        w0 = *(const u32*)p;
        w1 = *(const u32*)(p + D_DIM);
        w2 = *(const u32*)(p + 2 * D_DIM);
      }
      // issue x prefetch for chunk k (H-map; consumed at iter k+1)
      if (t >= 64)            xv1 = *(const float2*)(x + (size_t)((k * 32 + s1) * 16 + b) * D_DIM + d0 + ch1);
      if (t >= 64 && t < 128) xv2 = *(const float2*)(x + (size_t)((k * 32 + s2) * 16 + b) * D_DIM + d0 + ch2);
    }
    asm volatile("s_waitcnt lgkmcnt(0)" ::: "memory");
    __builtin_amdgcn_s_barrier();      // bar1: LDS[cur] ready; sCC/sG2[prv] stable

    if (k < 32 && t < 32) {   // S: lane t owns chain t; walk 32 steps from registers
      float lu[16], lg[16];
#pragma unroll
      for (int q = 0; q < 16; ++q) { lu[q] = sU0[cur][t][q]; lg[q] = sG1[cur][t][q]; }
#pragma unroll
      for (int q = 0; q < 16; ++q) {
        creg = (creg - lu[q]) * lg[q] + lu[q];
        sCC[cur][t][q] = creg;
      }
#pragma unroll
      for (int q = 0; q < 16; ++q) { lu[q] = sU0[cur][t][16 + q]; lg[q] = sG1[cur][t][16 + q]; }
#pragma unroll
      for (int q = 0; q < 16; ++q) {
        creg = (creg - lu[q]) * lg[q] + lu[q];
        sCC[cur][t][16 + q] = creg;
      }
    }
    if (k >= 1 && t >= 64) {  // H: emit h for chunk k-1 (concurrent with S)
      {
        const size_t m = (size_t)(((k - 1) * 32 + s1) * 16 + b);
        float ca  = sCC[prv][ch1][s1];
        float cbv = sCC[prv][ch1 + 1][s1];
        float ga  = sG2[prv][ch1][s1];
        float gb  = sG2[prv][ch1 + 1][s1];
        float2 hv;
        hv.x = (ftanh(ca) - xc1.x) * ga + xc1.x;
        hv.y = (ftanh(cbv) - xc1.y) * gb + xc1.y;
        *(float2*)(h + m * D_DIM + d0 + ch1) = hv;
      }
      if (t < 128) {
        const size_t m = (size_t)(((k - 1) * 32 + s2) * 16 + b);
        float ca  = sCC[prv][ch2][s2];
        float cbv = sCC[prv][ch2 + 1][s2];
        float ga  = sG2[prv][ch2][s2];
        float gb  = sG2[prv][ch2 + 1][s2];
        float2 hv;
        hv.x = (ftanh(ca) - xc2.x) * ga + xc2.x;
        hv.y = (ftanh(cbv) - xc2.y) * gb + xc2.y;
        *(float2*)(h + m * D_DIM + d0 + ch2) = hv;
      }
    }
    asm volatile("s_waitcnt lgkmcnt(0)" ::: "memory");
    __builtin_amdgcn_s_barrier();      // bar2: protects LDS[prv] before A(k+1) overwrite

    if (k == 32 && t < 32) clast[cb * 32 + t] = creg;
  }
}

extern "C" void kernel_launch(void* const* d_in, const int* in_sizes, int n_in,
                              void* d_out, int out_size, void* d_ws, size_t ws_size,
                              hipStream_t stream) {
  const float* x = (const float*)d_in[0];     // L*B*D
  const float* W = (const float*)d_in[1];     // K x 3D
  const float* bias = (const float*)d_in[2];  // 2D
  const float* c0 = (const float*)d_in[3];    // B*D
  float* out = (float*)d_out;

  char* ws = (char*)d_ws;
  u16* xb = (u16*)ws;                               // 32 MiB
  u16* wt = (u16*)(ws + 33554432);                  // 6 MiB
  u16* U = (u16*)(ws + 33554432 + 6291456);         // 96 MiB

  cvt_fused<<<16384 + 768, 256, 0, stream>>>((const float4*)x, (ushort4*)xb, W, wt);
  gemm_kernel<<<dim3(N_DIM / 256, M_DIM / 256), 512, 0, stream>>>(xb, wt, U);
  sru_onepass<<<512, 512, 0, stream>>>(U, x, bias, c0, out, out + (size_t)M_DIM * D_DIM);
}

// Round 13
// 253.723 us; speedup vs baseline: 1.0864x; 1.0060x over previous
//
#include <hip/hip_runtime.h>

#define L_DIM 1024
#define B_DIM 16
#define D_DIM 1024
#define K_DIM 1024            // = D
#define N_DIM 3072            // = 3*D
#define M_DIM (L_DIM * B_DIM) // 16384
#define CHAINS 16384          // B*D

typedef float f32x4 __attribute__((ext_vector_type(4)));
typedef __bf16 bf16x8 __attribute__((ext_vector_type(8)));
typedef unsigned short u16;
typedef unsigned int u32;

__device__ __forceinline__ u16 f2bf(float f) {
  u32 u = __float_as_uint(f);
  u = u + 0x7FFFu + ((u >> 16) & 1u);   // round-to-nearest-even
  return (u16)(u >> 16);
}
__device__ __forceinline__ float bf2f(u16 v) {
  return __uint_as_float(((u32)v) << 16);
}
__device__ __forceinline__ float bf2f_lo(u32 v) {
  return __uint_as_float(v << 16);
}
__device__ __forceinline__ float bf2f_hi(u32 v) {
  return __uint_as_float(v & 0xffff0000u);
}
__device__ __forceinline__ float fexp(float v) {
  return __builtin_amdgcn_exp2f(v * 1.4426950408889634f);
}
__device__ __forceinline__ float sigm(float z) {
  return __builtin_amdgcn_rcpf(1.0f + fexp(-z));
}
__device__ __forceinline__ float ftanh(float v) {
  return 1.0f - 2.0f * __builtin_amdgcn_rcpf(1.0f + fexp(2.0f * v));
}

// ---------------- fused converts: x cast (blocks 0..16383) + W permute (blocks 16384..17151) ----------------
__global__ __launch_bounds__(256) void cvt_fused(const float4* __restrict__ xin,
                                                 ushort4* __restrict__ xout,
                                                 const float* __restrict__ W,
                                                 u16* __restrict__ Wt) {
  if (blockIdx.x < 16384) {
    int i = blockIdx.x * 256 + threadIdx.x;
    float4 v = xin[i];
    ushort4 o;
    o.x = f2bf(v.x); o.y = f2bf(v.y); o.z = f2bf(v.z); o.w = f2bf(v.w);
    xout[i] = o;
  } else {
    __shared__ float tile[64][65];
    int wb = blockIdx.x - 16384;       // 0..767
    int c0 = (wb % 48) * 64;           // N block
    int r0 = (wb / 48) * 64;           // K block
    int tx = threadIdx.x & 63;
    int ty = threadIdx.x >> 6;
#pragma unroll
    for (int i = 0; i < 16; ++i) {
      int row = i * 4 + ty;
      tile[row][tx] = W[(size_t)(r0 + row) * N_DIM + c0 + tx];
    }
    __syncthreads();
#pragma unroll
    for (int i = 0; i < 16; ++i) {
      int crow = i * 4 + ty;
      int c = c0 + crow;
      int nprime = (c % 3) * D_DIM + (c / 3);
      Wt[(size_t)nprime * K_DIM + r0 + tx] = f2bf(tile[tx][crow]);
    }
  }
}

// ---------------- GEMM: 256x256 tile, BK=64, ONE barrier per tile, B triple-buffered --------
// (round-11 version, byte-identical — 99-112 us band, MfmaUtil ~40-45%, conflicts 0)

#define AS1 __attribute__((address_space(1)))
#define AS3 __attribute__((address_space(3)))
#define STAGE(gp, lp) do { \
  __builtin_amdgcn_global_load_lds((const AS1 void*)(gp), (AS3 void*)(lp), 16, 0, 0); \
  __builtin_amdgcn_global_load_lds((const AS1 void*)((gp) + (size_t)64 * K_DIM), \
                                   (AS3 void*)((lp) + 4096), 16, 0, 0); \
} while (0)

#define QUAD(AI, JB, BF) \
  _Pragma("unroll") \
  for (int i = 0; i < 4; ++i) { \
    _Pragma("unroll") \
    for (int j = 0; j < 2; ++j) { \
      acc[AI + i][JB + j] = __builtin_amdgcn_mfma_f32_16x16x32_bf16(aF[i][0], BF[j][0], acc[AI + i][JB + j], 0, 0, 0); \
      acc[AI + i][JB + j] = __builtin_amdgcn_mfma_f32_16x16x32_bf16(aF[i][1], BF[j][1], acc[AI + i][JB + j], 0, 0, 0); \
    } \
  }

__global__ __launch_bounds__(512, 2) void gemm_kernel(const u16* __restrict__ A,
                                                      const u16* __restrict__ Bt,
                                                      u16* __restrict__ U) {
  __shared__ __align__(16) u16 sm[81920];   // 160 KiB: A[2][16384] @0, B[3][16384] @32768
  const int tid = threadIdx.x;
  const int wave = tid >> 6;
  const int lane = tid & 63;
  const int wm = wave >> 2;        // 0..1  (M)
  const int wn = wave & 3;         // 0..3  (N)
  const int quad = lane >> 4;
  const int l16 = lane & 15;

  // XCD-aware bijective swizzle: 768 blocks, 96 per XCD = 8 contiguous M-rows x 12 N.
  const int flat = blockIdx.y * 12 + blockIdx.x;
  const int swz = (flat & 7) * 96 + (flat >> 3);
  const int m0 = (swz / 12) * 256;
  const int n0 = (swz % 12) * 256;

  // staging source (per-thread): thread t covers HT rows rr and rr+64, 16 B each,
  // global k-slot pre-swizzled so linear LDS dest yields swizzled content.
  const int rr = tid >> 3;                      // 0..63
  const int slot = (tid & 7) ^ (rr & 7);
  const u16* gA = A + (size_t)(m0 + rr) * K_DIM + slot * 8;
  const u16* gB = Bt + (size_t)(n0 + rr) * K_DIM + slot * 8;

  // LDS stage dest bases (u16 units); HW adds lane*16 B.
  u16* ldsA = sm + wave * 512;
  u16* ldsB = sm + 32768 + wave * 512;

  // fragment read bases (swizzled column offsets)
  const int swzu = (l16 & 7) << 3;              // u16 units
  const int c0 = (quad * 8) ^ swzu;             // ks=0
  const int c1 = (32 + quad * 8) ^ swzu;        // ks=1
  const u16* pA = sm + (wm * 128 + l16) * 64;
  const u16* pB = sm + 32768 + (wn * 64 + l16) * 64;

  f32x4 acc[8][4] = {};

  // prologue: A0 -> Aslot0, B0 -> Bslot0, B1 -> Bslot1; vmcnt(4) leaves B1 in flight
  STAGE(gA, ldsA);                                   // A kt0 HT0
  STAGE(gA + (size_t)128 * K_DIM, ldsA + 8192);      // A kt0 HT1
  STAGE(gB, ldsB);                                   // B kt0 HT0
  STAGE(gB + (size_t)128 * K_DIM, ldsB + 8192);      // B kt0 HT1
  STAGE(gB + 64, ldsB + 16384);                      // B kt1 HT0
  STAGE(gB + (size_t)128 * K_DIM + 64, ldsB + 16384 + 8192); // B kt1 HT1
  asm volatile("s_waitcnt vmcnt(4)" ::: "memory");
  __builtin_amdgcn_s_barrier();

  int su = 0;   // B read slot  = u%3
  int st = 2;   // B stage slot = (u+2)%3
  for (int u = 0; u < 16; ++u) {
    const int abuf = u & 1;
    const int anb = abuf ^ 1;
    const u16* pAb = pA + abuf * 16384;
    const u16* pBb = pB + su * 16384;
    bf16x8 aF[4][2], bLo[2][2], bHi[2][2];

    // ---- ds_read A mt0-3 + all B; stage A[u+1] -> A slot anb ----
#pragma unroll
    for (int i = 0; i < 4; ++i) {
      aF[i][0] = *(const bf16x8*)(pAb + i * 1024 + c0);
      aF[i][1] = *(const bf16x8*)(pAb + i * 1024 + c1);
    }
#pragma unroll
    for (int j = 0; j < 2; ++j) {
      bLo[j][0] = *(const bf16x8*)(pBb + j * 1024 + c0);
      bLo[j][1] = *(const bf16x8*)(pBb + j * 1024 + c1);
      bHi[j][0] = *(const bf16x8*)(pBb + (2 + j) * 1024 + c0);
      bHi[j][1] = *(const bf16x8*)(pBb + (2 + j) * 1024 + c1);
    }
    if (u < 15) {
      STAGE(gA + (u + 1) * 64, ldsA + anb * 16384);
      STAGE(gA + (size_t)128 * K_DIM + (u + 1) * 64, ldsA + anb * 16384 + 8192);
    }
    __builtin_amdgcn_s_setprio(1);
    QUAD(0, 0, bLo)
    QUAD(0, 2, bHi)
    __builtin_amdgcn_s_setprio(0);

    // ---- ds_read A mt4-7; stage B[u+2] -> B slot st ----
#pragma unroll
    for (int i = 0; i < 4; ++i) {
      aF[i][0] = *(const bf16x8*)(pAb + (4 + i) * 1024 + c0);
      aF[i][1] = *(const bf16x8*)(pAb + (4 + i) * 1024 + c1);
    }
    if (u < 14) {
      STAGE(gB + (u + 2) * 64, ldsB + st * 16384);
      STAGE(gB + (size_t)128 * K_DIM + (u + 2) * 64, ldsB + st * 16384 + 8192);
    }
    __builtin_amdgcn_s_setprio(1);
    QUAD(4, 2, bHi)
    QUAD(4, 0, bLo)
    __builtin_amdgcn_s_setprio(0);

    // tile-end: A[u+1]+B[u+1] must be in LDS for next tile; B[u+2] stays in flight
    if (u < 14) {
      asm volatile("s_waitcnt vmcnt(4)" ::: "memory");
    } else if (u == 14) {
      asm volatile("s_waitcnt vmcnt(0)" ::: "memory");
    }
    __builtin_amdgcn_s_barrier();

    su = (su == 2) ? 0 : su + 1;
    st = (st == 2) ? 0 : st + 1;
  }

  // epilogue: C/D layout col=lane&15, row=(lane>>4)*4+r
#pragma unroll
  for (int i = 0; i < 8; ++i) {
#pragma unroll
    for (int j = 0; j < 4; ++j) {
      const int col = n0 + wn * 64 + j * 16 + l16;
      const int rb = m0 + wm * 128 + i * 16 + quad * 4;
#pragma unroll
      for (int r = 0; r < 4; ++r)
        U[(size_t)(rb + r) * N_DIM + col] = f2bf(acc[i][j][r]);
    }
  }
}

// ---------------- SRU one-pass scan: 64-chain full-line blocks + S || H + prefetch ----------
// 256 blocks x 1024 threads; block owns 64 chains (one b, 64 d) -> every wave's U-plane
// read is one full 128-B line (32 pair-lanes x 4 B), eliminating the half-line double-fetch
// of the 32-chain version (sibling half belonged to a drifting other block -> L2 eviction ->
// U fetched ~2x from HBM). Structure = round-12: A(k) unpack prefetched U -> LDS[cur], issue
// U[k+1]+x[k] prefetch; bar1; S(k) on wave 0 (64 lanes, full wave) || H(k-1) on threads
// 64-1023; bar2. H items = 1024: threads 64-1023 do item t-64, threads 64-127 also 960+(t-64).
// LDS [2][64][33] f32 x4 = 67.6 KB, 1024 threads -> 16 waves/CU.

__global__ __launch_bounds__(1024) void sru_onepass(const u16* __restrict__ U,
                                                    const float* __restrict__ x,
                                                    const float* __restrict__ bias,
                                                    const float* __restrict__ c0,
                                                    float* __restrict__ h,
                                                    float* __restrict__ clast) {
  __shared__ float sU0[2][64][33];
  __shared__ float sG1[2][64][33];
  __shared__ float sG2[2][64][33];
  __shared__ float sCC[2][64][33];

  const int flat = blockIdx.x;                   // 0..255; XCD-bijective (8 x 32)
  const int cb = (flat & 7) * 32 + (flat >> 3);  // chain-block 0..255
  const int b  = cb >> 4;                        // batch 0..15
  const int d0 = (cb & 15) << 6;                 // d base, step 64
  const int t  = threadIdx.x;
  const int s  = t >> 5;                         // A-map: step-in-chunk 0..31
  const int ch = (t & 31) * 2;                   // A-map: chain pair base 0..62
  const int d2 = d0 + ch;

  const float2 bb1 = *(const float2*)(bias + d2);
  const float2 bb2 = *(const float2*)(bias + D_DIM + d2);

  // H-map: thread t>=64 handles item1 = t-64 (0..959); threads 64..127 also item2 = 960+(t-64)
  const int i1 = t - 64;
  const int s1 = i1 >> 5, ch1 = (i1 & 31) * 2;
  const int i2 = 960 + (t - 64);
  const int s2 = i2 >> 5, ch2 = (i2 & 31) * 2;

  float creg = 0.0f;
  if (t < 64) creg = c0[cb * 64 + t];

  // prefetch chunk 0: U planes (A-map) and x (H-map)
  u32 w0, w1, w2;
  float2 xv1, xv2;
  {
    const size_t m = (size_t)(s * 16 + b);
    const u16* p = U + m * N_DIM + d2;
    w0 = *(const u32*)p;
    w1 = *(const u32*)(p + D_DIM);
    w2 = *(const u32*)(p + 2 * D_DIM);
  }
  if (t >= 64)             xv1 = *(const float2*)(x + (size_t)(s1 * 16 + b) * D_DIM + d0 + ch1);
  if (t >= 64 && t < 128)  xv2 = *(const float2*)(x + (size_t)(s2 * 16 + b) * D_DIM + d0 + ch2);

  for (int k = 0; k <= 32; ++k) {
    const int cur = k & 1;
    const int prv = cur ^ 1;

    float2 xc1 = xv1, xc2 = xv2;   // x[chunk k-1] for H below

    if (k < 32) {
      // A: unpack prefetched chunk k -> LDS[cur]
      sU0[cur][ch][s]     = bf2f_lo(w0);
      sU0[cur][ch + 1][s] = bf2f_hi(w0);
      sG1[cur][ch][s]     = sigm(bf2f_lo(w1) + bb1.x);
      sG1[cur][ch + 1][s] = sigm(bf2f_hi(w1) + bb1.y);
      sG2[cur][ch][s]     = sigm(bf2f_lo(w2) + bb2.x);
      sG2[cur][ch + 1][s] = sigm(bf2f_hi(w2) + bb2.y);
      if (k < 31) {   // issue U prefetch for chunk k+1
        const size_t m = (size_t)(((k + 1) * 32 + s) * 16 + b);
        const u16* p = U + m * N_DIM + d2;
        w0 = *(const u32*)p;
        w1 = *(const u32*)(p + D_DIM);
        w2 = *(const u32*)(p + 2 * D_DIM);
      }
      // issue x prefetch for chunk k (H-map; consumed at iter k+1)
      if (t >= 64)            xv1 = *(const float2*)(x + (size_t)((k * 32 + s1) * 16 + b) * D_DIM + d0 + ch1);
      if (t >= 64 && t < 128) xv2 = *(const float2*)(x + (size_t)((k * 32 + s2) * 16 + b) * D_DIM + d0 + ch2);
    }
    asm volatile("s_waitcnt lgkmcnt(0)" ::: "memory");
    __builtin_amdgcn_s_barrier();      // bar1: LDS[cur] ready; sCC/sG2[prv] stable

    if (k < 32 && t < 64) {   // S: wave 0, lane t owns chain t; walk 32 steps from registers
      float lu[16], lg[16];
#pragma unroll
      for (int q = 0; q < 16; ++q) { lu[q] = sU0[cur][t][q]; lg[q] = sG1[cur][t][q]; }
#pragma unroll
      for (int q = 0; q < 16; ++q) {
        creg = (creg - lu[q]) * lg[q] + lu[q];
        sCC[cur][t][q] = creg;
      }
#pragma unroll
      for (int q = 0; q < 16; ++q) { lu[q] = sU0[cur][t][16 + q]; lg[q] = sG1[cur][t][16 + q]; }
#pragma unroll
      for (int q = 0; q < 16; ++q) {
        creg = (creg - lu[q]) * lg[q] + lu[q];
        sCC[cur][t][16 + q] = creg;
      }
    }
    if (k >= 1 && t >= 64) {  // H: emit h for chunk k-1 (concurrent with S)
      {
        const size_t m = (size_t)(((k - 1) * 32 + s1) * 16 + b);
        float ca  = sCC[prv][ch1][s1];
        float cbv = sCC[prv][ch1 + 1][s1];
        float ga  = sG2[prv][ch1][s1];
        float gb  = sG2[prv][ch1 + 1][s1];
        float2 hv;
        hv.x = (ftanh(ca) - xc1.x) * ga + xc1.x;
        hv.y = (ftanh(cbv) - xc1.y) * gb + xc1.y;
        *(float2*)(h + m * D_DIM + d0 + ch1) = hv;
      }
      if (t < 128) {
        const size_t m = (size_t)(((k - 1) * 32 + s2) * 16 + b);
        float ca  = sCC[prv][ch2][s2];
        float cbv = sCC[prv][ch2 + 1][s2];
        float ga  = sG2[prv][ch2][s2];
        float gb  = sG2[prv][ch2 + 1][s2];
        float2 hv;
        hv.x = (ftanh(ca) - xc2.x) * ga + xc2.x;
        hv.y = (ftanh(cbv) - xc2.y) * gb + xc2.y;
        *(float2*)(h + m * D_DIM + d0 + ch2) = hv;
      }
    }
    asm volatile("s_waitcnt lgkmcnt(0)" ::: "memory");
    __builtin_amdgcn_s_barrier();      // bar2: protects LDS[prv] before A(k+1) overwrite

    if (k == 32 && t < 64) clast[cb * 64 + t] = creg;
  }
}

extern "C" void kernel_launch(void* const* d_in, const int* in_sizes, int n_in,
                              void* d_out, int out_size, void* d_ws, size_t ws_size,
                              hipStream_t stream) {
  const float* x = (const float*)d_in[0];     // L*B*D
  const float* W = (const float*)d_in[1];     // K x 3D
  const float* bias = (const float*)d_in[2];  // 2D
  const float* c0 = (const float*)d_in[3];    // B*D
  float* out = (float*)d_out;

  char* ws = (char*)d_ws;
  u16* xb = (u16*)ws;                               // 32 MiB
  u16* wt = (u16*)(ws + 33554432);                  // 6 MiB
  u16* U = (u16*)(ws + 33554432 + 6291456);         // 96 MiB

  cvt_fused<<<16384 + 768, 256, 0, stream>>>((const float4*)x, (ushort4*)xb, W, wt);
  gemm_kernel<<<dim3(N_DIM / 256, M_DIM / 256), 512, 0, stream>>>(xb, wt, U);
  sru_onepass<<<256, 1024, 0, stream>>>(U, x, bias, c0, out, out + (size_t)M_DIM * D_DIM);
}